// Round 15
// baseline (1014.018 us; speedup 1.0000x reference)
//
#include <hip/hip_runtime.h>

#define DD 64
#define GG 64
#define EPSV 1e-5f
#define SLOPE 0.01f

#define NRM_NPW 16

// binned CSR build
#define NRANGE 512
#define RSHIFT 8              // 256 nodes per range (512*256 = 131072 >= N)
#define NPR 256
#define ABLK 512              // edge-chunk blocks in phases A1/A3

typedef unsigned short ushort_t;
typedef unsigned int uint_t;
typedef float v2f __attribute__((ext_vector_type(2)));
typedef __attribute__((ext_vector_type(8))) short bf16x8;
typedef __attribute__((ext_vector_type(4))) float f32x4;

__device__ __forceinline__ ushort_t f2bf(float f) {
  uint_t u = __float_as_uint(f);
  uint_t r = (u + 0x7fffu + ((u >> 16) & 1u)) >> 16;   // round-to-nearest-even
  return (ushort_t)r;
}
__device__ __forceinline__ float bf2f(ushort_t s) { return __uint_as_float(((uint_t)s) << 16); }
__device__ __forceinline__ v2f unpk(uint_t u) {      // {lo,hi} bf16 pair -> 2 floats
  v2f r;
  r.x = __uint_as_float(u << 16);
  r.y = __uint_as_float(u & 0xffff0000u);
  return r;
}

// ---------- A1: per-(block,range) histograms, both directions, LDS-only atomics ----------
__global__ __launch_bounds__(256) void bin_count_kernel(const int* __restrict__ src,
                                                        const int* __restrict__ dst,
                                                        int* __restrict__ hist, int E) {
  __shared__ int cf[NRANGE], cb[NRANGE];
  for (int i=threadIdx.x; i<NRANGE; i+=256) { cf[i]=0; cb[i]=0; }
  __syncthreads();
  int epb = (E + ABLK-1)/ABLK;
  int lo = blockIdx.x*epb, hi = lo+epb; if (hi>E) hi=E;
  for (int e=lo+threadIdx.x; e<hi; e+=256) {
    int d = __builtin_nontemporal_load(&dst[e]);
    int s = __builtin_nontemporal_load(&src[e]);
    atomicAdd(&cf[d>>RSHIFT], 1);
    atomicAdd(&cb[s>>RSHIFT], 1);
  }
  __syncthreads();
  for (int r=threadIdx.x; r<NRANGE; r+=256) {
    hist[(size_t)r*ABLK + blockIdx.x]            = cf[r];
    hist[(size_t)(NRANGE+r)*ABLK + blockIdx.x]   = cb[r];
  }
}

// ---------- generic 2-level scan over hist (M = 2*NRANGE*ABLK = 524288) ----------
__global__ void block_sum_kernel(const int* __restrict__ v, int* __restrict__ partial, int M) {
  __shared__ int sm[1024];
  int i = blockIdx.x*1024 + threadIdx.x;
  sm[threadIdx.x] = (i<M) ? v[i] : 0;
  __syncthreads();
  for (int s=512; s>0; s>>=1) {
    if (threadIdx.x < s) sm[threadIdx.x] += sm[threadIdx.x+s];
    __syncthreads();
  }
  if (threadIdx.x==0) partial[blockIdx.x] = sm[0];
}

__global__ void scan_partial_kernel(int* __restrict__ partial, int nb) {  // 512 threads
  __shared__ int sm[512];
  int t = threadIdx.x;
  int v = (t<nb) ? partial[t] : 0;
  int orig = v;
  sm[t] = v; __syncthreads();
  for (int off=1; off<512; off<<=1) {
    int a = (t>=off) ? sm[t-off] : 0;
    __syncthreads();
    v += a; sm[t] = v;
    __syncthreads();
  }
  if (t<nb) partial[t] = v - orig;   // exclusive block offsets
}

__global__ void scan_apply_kernel(const int* __restrict__ v, const int* __restrict__ partial,
                                  int* __restrict__ out, int M) {
  __shared__ int sm[1024];
  int i = blockIdx.x*1024 + threadIdx.x;
  int x = (i<M) ? v[i] : 0;
  int orig = x;
  sm[threadIdx.x] = x; __syncthreads();
  for (int off=1; off<1024; off<<=1) {
    int a = (threadIdx.x>=off) ? sm[threadIdx.x-off] : 0;
    __syncthreads();
    x += a; sm[threadIdx.x] = x;
    __syncthreads();
  }
  if (i<M) out[i] = x - orig + partial[blockIdx.x];   // exclusive scan
}

// ---------- A3: scatter (key,val) records into reserved segments, LDS-only atomics ----------
__global__ __launch_bounds__(256) void bin_scatter_kernel(const int* __restrict__ src,
                                                          const int* __restrict__ dst,
                                                          const int* __restrict__ offs,
                                                          int2* __restrict__ staged, int E) {
  __shared__ int ofF[NRANGE], ofB[NRANGE];
  for (int r=threadIdx.x; r<NRANGE; r+=256) {
    ofF[r] = offs[(size_t)r*ABLK + blockIdx.x];
    ofB[r] = offs[(size_t)(NRANGE+r)*ABLK + blockIdx.x];
  }
  __syncthreads();
  int epb = (E + ABLK-1)/ABLK;
  int lo = blockIdx.x*epb, hi = lo+epb; if (hi>E) hi=E;
  for (int e=lo+threadIdx.x; e<hi; e+=256) {
    int d = __builtin_nontemporal_load(&dst[e]);
    int s = __builtin_nontemporal_load(&src[e]);
    int pf = atomicAdd(&ofF[d>>RSHIFT], 1);
    staged[pf] = make_int2(d, s);              // fwd record: key=dst, val=src
    int pb = atomicAdd(&ofB[s>>RSHIFT], 1);
    staged[pb] = make_int2(s, d);              // bwd record: key=src, val=dst
  }
}

// ---------- B: per-range counting sort -> rp (coalesced) + col (L2-window scatter) ----------
__global__ __launch_bounds__(256) void range_fill_kernel(const int2* __restrict__ staged,
                                                         const int* __restrict__ offs,
                                                         int* __restrict__ rp_f, int* __restrict__ rp_b,
                                                         int* __restrict__ col_f, int* __restrict__ col_b,
                                                         int N, int E) {
  __shared__ int cnt[NPR], noff[NPR], sc[NPR];
  int lr = blockIdx.x;
  int d = lr >> 9, r = lr & (NRANGE-1);
  int start = offs[(size_t)lr*ABLK];
  int end   = (lr+1 < 2*NRANGE) ? offs[(size_t)(lr+1)*ABLK] : 2*E;
  int t = threadIdx.x;
  cnt[t] = 0; __syncthreads();
  for (int k=start+t; k<end; k+=256) {
    int key = staged[k].x;
    atomicAdd(&cnt[key & (NPR-1)], 1);
  }
  __syncthreads();
  int x = cnt[t]; sc[t] = x; __syncthreads();
  for (int off=1; off<NPR; off<<=1) {
    int a = (t>=off) ? sc[t-off] : 0;
    __syncthreads();
    x += a; sc[t] = x;
    __syncthreads();
  }
  noff[t] = x - cnt[t];
  __syncthreads();
  int base = d ? (start - E) : start;
  int node = (r << RSHIFT) + t;
  int* rp = d ? rp_b : rp_f;
  if (node < N)       rp[node] = base + noff[t];
  else if (node == N) rp[N]    = base + noff[t];
  cnt[t] = 0; __syncthreads();
  int* col = d ? col_b : col_f;
  for (int k=start+t; k<end; k+=256) {
    int2 rec = staged[k];
    int li = rec.x & (NPR-1);
    int rank = atomicAdd(&cnt[li], 1);
    col[base + noff[li] + rank] = rec.y;
  }
}

__global__ void cnt_kernel(const int* __restrict__ batch, int* __restrict__ cnt, int N) {
  __shared__ int hist[GG];
  if (threadIdx.x < GG) hist[threadIdx.x] = 0;
  __syncthreads();
  int i = blockIdx.x*blockDim.x + threadIdx.x;
  int stride = gridDim.x*blockDim.x;
  for (int n=i; n<N; n+=stride) atomicAdd(&hist[batch[n]], 1);
  __syncthreads();
  if (threadIdx.x < GG) atomicAdd(&cnt[threadIdx.x], hist[threadIdx.x]);
}

// ----------------- fp32 -> bf16 shadow -----------------
__global__ void tobf16_kernel(const float* __restrict__ in, ushort_t* __restrict__ out, int M) {
  int i = blockIdx.x*blockDim.x + threadIdx.x;
  int stride = gridDim.x*blockDim.x;
  for (int k=i; k<M; k+=stride) out[k] = f2bf(in[k]);
}

// ----------------- weight pack: [Wl;Wr] (K=128) -> MFMA B-fragment layout -----------------
// Wb[layer][kb][col][j] bf16, kb=k/8 (16), col (64), j=k%8 (8): lane reads 16B contiguous.
__global__ void wpack_kernel(const float* __restrict__ Wl, const float* __restrict__ Wr,
                             ushort_t* __restrict__ Wb) {
  int l = blockIdx.x;
  const float* wl = Wl + (size_t)l*4096;
  const float* wr = Wr + (size_t)l*4096;
  ushort_t* out = Wb + (size_t)l*8192;
  for (int idx = threadIdx.x; idx < 8192; idx += 256) {
    int kb = idx >> 9, rem = idx & 511, col = rem >> 3, j = rem & 7;
    int k = kb*8 + j;
    float v = (k < 64) ? wl[(size_t)k*64+col] : wr[(size_t)(k-64)*64+col];
    out[idx] = f2bf(v);
  }
}

// ----------------- gather: one wave per node; 32-bit offsets + packed accumulate --------
__global__ __launch_bounds__(256) void gather_kernel(
    const ushort_t* __restrict__ hb,
    const int* __restrict__ rp_f, const int* __restrict__ col_f,
    const int* __restrict__ rp_b, const int* __restrict__ col_b,
    ushort_t* __restrict__ sbufb, int N)
{
  int w = (blockIdx.x*(blockDim.x>>6)) + (threadIdx.x>>6);   // node = global wave id
  if (w >= N) return;
  int lane = threadIdx.x & 63;
  int qt = lane >> 4;        // quarter 0..3
  int g  = lane & 15;        // feature quad: features 4g..4g+3
  const char* hbb = (const char*)hb;
  uint_t goff = (uint_t)g << 3;     // byte offset of this lane's quad within a row

  v2f a01={0.f,0.f}, a23={0.f,0.f}, c01={0.f,0.f}, c23={0.f,0.f};
  int degf, degb;

  {
    int s0 = rp_f[w], e0 = rp_f[w+1];
    degf = e0 - s0;
    for (int base=s0; base<e0; base+=64) {
      int m = e0-base; if (m>64) m=64;
      int jv = (lane<m) ? col_f[base+lane] : 0;
      int q=0;
      for (; 4*q+16 <= m; q+=4) {
        int j0=__shfl(jv,4*q+qt),    j1=__shfl(jv,4*q+4+qt);
        int j2=__shfl(jv,4*q+8+qt),  j3=__shfl(jv,4*q+12+qt);
        uint2 v0 = *(const uint2*)(hbb + ((((uint_t)j0)<<7) | goff));
        uint2 v1 = *(const uint2*)(hbb + ((((uint_t)j1)<<7) | goff));
        uint2 v2 = *(const uint2*)(hbb + ((((uint_t)j2)<<7) | goff));
        uint2 v3 = *(const uint2*)(hbb + ((((uint_t)j3)<<7) | goff));
        a01 += unpk(v0.x); a23 += unpk(v0.y);
        a01 += unpk(v1.x); a23 += unpk(v1.y);
        a01 += unpk(v2.x); a23 += unpk(v2.y);
        a01 += unpk(v3.x); a23 += unpk(v3.y);
      }
      for (; 4*q+qt < m; ++q) {
        int j=__shfl(jv,4*q+qt);
        uint2 v = *(const uint2*)(hbb + ((((uint_t)j)<<7) | goff));
        a01 += unpk(v.x); a23 += unpk(v.y);
      }
    }
  }
  {
    int s1 = rp_b[w], e1 = rp_b[w+1];
    degb = e1 - s1;
    for (int base=s1; base<e1; base+=64) {
      int m = e1-base; if (m>64) m=64;
      int jv = (lane<m) ? col_b[base+lane] : 0;
      int q=0;
      for (; 4*q+16 <= m; q+=4) {
        int j0=__shfl(jv,4*q+qt),    j1=__shfl(jv,4*q+4+qt);
        int j2=__shfl(jv,4*q+8+qt),  j3=__shfl(jv,4*q+12+qt);
        uint2 v0 = *(const uint2*)(hbb + ((((uint_t)j0)<<7) | goff));
        uint2 v1 = *(const uint2*)(hbb + ((((uint_t)j1)<<7) | goff));
        uint2 v2 = *(const uint2*)(hbb + ((((uint_t)j2)<<7) | goff));
        uint2 v3 = *(const uint2*)(hbb + ((((uint_t)j3)<<7) | goff));
        c01 += unpk(v0.x); c23 += unpk(v0.y);
        c01 += unpk(v1.x); c23 += unpk(v1.y);
        c01 += unpk(v2.x); c23 += unpk(v2.y);
        c01 += unpk(v3.x); c23 += unpk(v3.y);
      }
      for (; 4*q+qt < m; ++q) {
        int j=__shfl(jv,4*q+qt);
        uint2 v = *(const uint2*)(hbb + ((((uint_t)j)<<7) | goff));
        c01 += unpk(v.x); c23 += unpk(v.y);
      }
    }
  }

  float df = fmaxf((float)degf, 1.f);
  float db = fmaxf((float)degb, 1.f);
  float s0v = 0.5f*(a01.x/df + c01.x/db);
  float s1v = 0.5f*(a01.y/df + c01.y/db);
  float s2v = 0.5f*(a23.x/df + c23.x/db);
  float s3v = 0.5f*(a23.y/df + c23.y/db);
  s0v += __shfl_xor(s0v,16); s0v += __shfl_xor(s0v,32);
  s1v += __shfl_xor(s1v,16); s1v += __shfl_xor(s1v,32);
  s2v += __shfl_xor(s2v,16); s2v += __shfl_xor(s2v,32);
  s3v += __shfl_xor(s3v,16); s3v += __shfl_xor(s3v,32);
  if (qt==0) {
    uint_t p0 = (uint_t)f2bf(s0v) | ((uint_t)f2bf(s1v) << 16);
    uint_t p1 = (uint_t)f2bf(s2v) | ((uint_t)f2bf(s3v) << 16);
    *(uint2*)&((uint_t*)sbufb)[(size_t)w*32 + 2*g] = make_uint2(p0, p1);
  }
}

// --------- MFMA gemm: t[64 nodes,64] = [s|h](64x128) @ Wb(128x64) + bias; stats fused ---------
// Block: 256 thr = 4 waves; wave w owns node strip [blk*64+16w, +16), all 4 col-tiles.
// No LDS. A-fragments direct from sbufb/hb (16B/lane); B from packed Wb.
__global__ __launch_bounds__(256) void gemm_kernel(
    const ushort_t* __restrict__ hb, const ushort_t* __restrict__ sbufb,
    const ushort_t* __restrict__ Wb, const float* __restrict__ bias,
    const int* __restrict__ batch,
    ushort_t* __restrict__ tb, float* __restrict__ gsum, float* __restrict__ gsq, int N)
{
  int wid = threadIdx.x >> 6;
  int lane = threadIdx.x & 63;
  int lrow = lane & 15;        // A-row within strip / C-col (feat) within tile
  int lk   = lane >> 4;        // k-subgroup
  int strip = blockIdx.x*64 + wid*16;

  int arow = strip + lrow; if (arow >= N) arow = N-1;   // clamp; OOB rows masked at store
  const bf16x8* sfrag = (const bf16x8*)(sbufb + (size_t)arow*DD);
  const bf16x8* hfrag = (const bf16x8*)(hb    + (size_t)arow*DD);
  bf16x8 a0 = sfrag[lk];       // s k 0..31   (lane elems lk*8..lk*8+7)
  bf16x8 a1 = sfrag[4+lk];     // s k 32..63
  bf16x8 a2 = hfrag[lk];       // h k 64..95
  bf16x8 a3 = hfrag[4+lk];     // h k 96..127

  const bf16x8* wbp = (const bf16x8*)Wb;   // unit index = kb*64 + col
  f32x4 acc[4];
  #pragma unroll
  for (int t=0; t<4; ++t) acc[t] = (f32x4){0.f,0.f,0.f,0.f};

  #pragma unroll
  for (int t=0; t<4; ++t) {
    int col = t*16 + lrow;
    bf16x8 b0 = wbp[(0*4+lk)*64 + col];
    bf16x8 b1 = wbp[(1*4+lk)*64 + col];
    bf16x8 b2 = wbp[(2*4+lk)*64 + col];
    bf16x8 b3 = wbp[(3*4+lk)*64 + col];
    acc[t] = __builtin_amdgcn_mfma_f32_16x16x32_bf16(a0, b0, acc[t], 0,0,0);
    acc[t] = __builtin_amdgcn_mfma_f32_16x16x32_bf16(a1, b1, acc[t], 0,0,0);
    acc[t] = __builtin_amdgcn_mfma_f32_16x16x32_bf16(a2, b2, acc[t], 0,0,0);
    acc[t] = __builtin_amdgcn_mfma_f32_16x16x32_bf16(a3, b3, acc[t], 0,0,0);
  }

  // C/D: node = strip + lk*4 + r, feat = t*16 + lrow  [verified mapping]
  int bt[4];
  #pragma unroll
  for (int r=0; r<4; ++r) {
    int node = strip + lk*4 + r;
    bt[r] = (node < N) ? batch[node] : -1;
  }
  #pragma unroll
  for (int t=0; t<4; ++t) {
    int feat = t*16 + lrow;
    float bv = bias[feat];
    int gcur = -1; float ga=0.f, qa=0.f;
    #pragma unroll
    for (int r=0; r<4; ++r) {
      if (bt[r] < 0) break;
      int node = strip + lk*4 + r;
      float v = acc[t][r] + bv;
      tb[(size_t)node*DD + feat] = f2bf(v);
      if (bt[r] != gcur) {
        if (gcur >= 0) { atomicAdd(&gsum[gcur*DD+feat], ga); atomicAdd(&gsq[gcur*DD+feat], qa); }
        gcur = bt[r]; ga = 0.f; qa = 0.f;
      }
      ga += v; qa += v*v;
    }
    if (gcur >= 0) { atomicAdd(&gsum[gcur*DD+feat], ga); atomicAdd(&gsq[gcur*DD+feat], qa); }
  }
}

// ---- GraphNorm (var from sums) + leaky + residual, bf16 state in-place; last fuses pool ----
__global__ void norm2_kernel(const ushort_t* __restrict__ tb,
                             const float* __restrict__ gsum, const float* __restrict__ gsq,
                             const int* __restrict__ cnt, const int* __restrict__ batch,
                             const float* __restrict__ gw, const float* __restrict__ gb,
                             const float* __restrict__ gms,
                             ushort_t* __restrict__ hb,
                             float* __restrict__ pout,
                             int resid, int last, int N)
{
  int wid = (blockIdx.x*blockDim.x + threadIdx.x) >> 6;
  int lane = threadIdx.x & 63;
  int base = wid*NRM_NPW;
  if (base >= N) return;
  float wv = gw[lane], bv = gb[lane], msv = gms[lane];
  float cms = msv*(2.f - msv);
  int gcur=-1; float rs=0.f, mean=0.f, pacc=0.f;
  int end = base+NRM_NPW; if (end>N) end=N;
  for (int node=base; node<end; ++node) {
    int g = batch[node];
    if (g!=gcur) {
      if (last && gcur>=0) atomicAdd(&pout[gcur*DD+lane], pacc);
      pacc = 0.f;
      float invc = 1.f/fmaxf((float)cnt[g],1.f);
      mean = gsum[g*DD+lane]*invc;
      float msq = gsq[g*DD+lane]*invc;
      float var = msq - cms*mean*mean;         // E[(t-ms*mean)^2]
      rs = rsqrtf(var + EPSV);
      gcur=g;
    }
    float u = bf2f(tb[(size_t)node*DD+lane]) - msv*mean;
    float y = wv*u*rs + bv;
    y = (y>=0.f) ? y : SLOPE*y;
    float hv = resid ? (bf2f(hb[(size_t)node*DD+lane]) + y) : y;
    if (last) {
      pacc += hv;                  // final h never re-read: pool only
    } else {
      hb[(size_t)node*DD+lane] = f2bf(hv);   // in-place: all layer-i readers done
    }
  }
  if (last && gcur>=0) atomicAdd(&pout[gcur*DD+lane], pacc);
}

__global__ void finalize_kernel(const float* __restrict__ pout, const int* __restrict__ cnt,
                                float* __restrict__ out)
{
  int i = blockIdx.x*blockDim.x + threadIdx.x;
  if (i < GG*DD) {
    float invc = 1.f/fmaxf((float)cnt[i>>6],1.f);
    out[i] = pout[i]*invc;
  }
}

extern "C" void kernel_launch(void* const* d_in, const int* in_sizes, int n_in,
                              void* d_out, int out_size, void* d_ws, size_t ws_size,
                              hipStream_t stream)
{
  const float* x    = (const float*)d_in[0];
  const int*  ei    = (const int*)d_in[1];
  const int*  batch = (const int*)d_in[2];
  const float* W_l  = (const float*)d_in[3];
  const float* W_r  = (const float*)d_in[4];
  const float* bias = (const float*)d_in[5];
  const float* gn_w = (const float*)d_in[6];
  const float* gn_b = (const float*)d_in[7];
  const float* gn_ms= (const float*)d_in[8];

  int N = in_sizes[2];
  int E = in_sizes[1]/2;
  int L = in_sizes[5]/DD;
  const int* src = ei;
  const int* dst = ei + E;

  // ---- workspace layout: zero-zone first (single memset) ----
  char* p = (char*)d_ws;
  int*   cnt   = (int*)p;   p += GG*4;
  float* gsum  = (float*)p; p += (size_t)L*GG*DD*4;
  float* gsq   = (float*)p; p += (size_t)L*GG*DD*4;
  float* pout  = (float*)p; p += GG*DD*4;
  size_t zeroBytes = (char*)p - (char*)d_ws;

  int2* staged = (int2*)p; p += (size_t)2*E*8;            // CSR build records (25.6MB)
  ushort_t* tb    = (ushort_t*)p; p += (size_t)N*DD*2;
  ushort_t* sbufb = (ushort_t*)p; p += (size_t)N*DD*2;
  ushort_t* hb    = (ushort_t*)p; p += (size_t)N*DD*2;
  ushort_t* wb    = (ushort_t*)p; p += (size_t)L*8192*2;  // packed MFMA weights
  int* rp_f    = (int*)p; p += (size_t)(N+1)*4;
  int* rp_b    = (int*)p; p += (size_t)(N+1)*4;
  int* col_f   = (int*)p; p += (size_t)E*4;
  int* col_b   = (int*)p; p += (size_t)E*4;
  int* hist    = (int*)p; p += (size_t)2*NRANGE*ABLK*4;   // 2MB
  int* offs    = (int*)p; p += (size_t)2*NRANGE*ABLK*4;   // 2MB
  int* partial = (int*)p; p += 512*4;

  hipMemsetAsync(d_ws, 0, zeroBytes, stream);

  const int M = 2*NRANGE*ABLK;  // 524288
  bin_count_kernel<<<ABLK, 256, 0, stream>>>(src, dst, hist, E);
  block_sum_kernel<<<(M+1023)/1024, 1024, 0, stream>>>(hist, partial, M);
  scan_partial_kernel<<<1, 512, 0, stream>>>(partial, (M+1023)/1024);
  scan_apply_kernel<<<(M+1023)/1024, 1024, 0, stream>>>(hist, partial, offs, M);
  bin_scatter_kernel<<<ABLK, 256, 0, stream>>>(src, dst, offs, staged, E);
  range_fill_kernel<<<2*NRANGE, 256, 0, stream>>>(staged, offs, rp_f, rp_b, col_f, col_b, N, E);

  cnt_kernel<<<391, 256, 0, stream>>>(batch, cnt, N);
  tobf16_kernel<<<2048, 256, 0, stream>>>(x, hb, N*DD);
  wpack_kernel<<<L, 256, 0, stream>>>(W_l, W_r, wb);

  int gthBlocks = (N + 3)/4;           // 4 waves (nodes) per 256-thread block
  int agBlocks = (N + 63)/64;          // 64 nodes per 256-thread MFMA block
  int nrmWaves = (N + NRM_NPW-1)/NRM_NPW;
  int nrmBlocks = (nrmWaves+3)/4;

  for (int i=0; i<L; ++i) {
    float* gsum_i = gsum + (size_t)i*GG*DD;
    float* gsq_i  = gsq  + (size_t)i*GG*DD;
    int last = (i==L-1) ? 1 : 0;
    gather_kernel<<<gthBlocks, 256, 0, stream>>>(hb, rp_f, col_f, rp_b, col_b, sbufb, N);
    gemm_kernel<<<agBlocks, 256, 0, stream>>>(hb, sbufb, wb + (size_t)i*8192,
                                              bias+(size_t)i*DD, batch, tb, gsum_i, gsq_i, N);
    norm2_kernel<<<nrmBlocks, 256, 0, stream>>>(tb, gsum_i, gsq_i, cnt, batch,
                                                gn_w+(size_t)i*DD, gn_b+(size_t)i*DD,
                                                gn_ms+(size_t)i*DD,
                                                hb, pout, (i>=2)?1:0, last, N);
  }
  finalize_kernel<<<16, 256, 0, stream>>>(pout, cnt, (float*)d_out);
}

// Round 16
// 708.660 us; speedup vs baseline: 1.4309x; 1.4309x over previous
//
#include <hip/hip_runtime.h>

#define DD 64
#define GG 64
#define EPSV 1e-5f
#define SLOPE 0.01f

#define NRM_NPW 16

// binned CSR build
#define NRANGE 512
#define RSHIFT 8              // 256 nodes per range (512*256 = 131072 >= N)
#define NPR 256
#define ABLK 512              // edge-chunk blocks in phases A1/A3

typedef unsigned short ushort_t;
typedef unsigned int uint_t;
typedef float v2f __attribute__((ext_vector_type(2)));
typedef __attribute__((ext_vector_type(8))) short bf16x8;
typedef __attribute__((ext_vector_type(4))) float f32x4;

__device__ __forceinline__ ushort_t f2bf(float f) {
  uint_t u = __float_as_uint(f);
  uint_t r = (u + 0x7fffu + ((u >> 16) & 1u)) >> 16;   // round-to-nearest-even
  return (ushort_t)r;
}
__device__ __forceinline__ float bf2f(ushort_t s) { return __uint_as_float(((uint_t)s) << 16); }
__device__ __forceinline__ v2f unpk(uint_t u) {      // {lo,hi} bf16 pair -> 2 floats
  v2f r;
  r.x = __uint_as_float(u << 16);
  r.y = __uint_as_float(u & 0xffff0000u);
  return r;
}

// ---------- A1: per-(block,range) histograms, both directions, LDS-only atomics ----------
__global__ __launch_bounds__(256) void bin_count_kernel(const int* __restrict__ src,
                                                        const int* __restrict__ dst,
                                                        int* __restrict__ hist, int E) {
  __shared__ int cf[NRANGE], cb[NRANGE];
  for (int i=threadIdx.x; i<NRANGE; i+=256) { cf[i]=0; cb[i]=0; }
  __syncthreads();
  int epb = (E + ABLK-1)/ABLK;
  int lo = blockIdx.x*epb, hi = lo+epb; if (hi>E) hi=E;
  for (int e=lo+threadIdx.x; e<hi; e+=256) {
    int d = __builtin_nontemporal_load(&dst[e]);
    int s = __builtin_nontemporal_load(&src[e]);
    atomicAdd(&cf[d>>RSHIFT], 1);
    atomicAdd(&cb[s>>RSHIFT], 1);
  }
  __syncthreads();
  for (int r=threadIdx.x; r<NRANGE; r+=256) {
    hist[(size_t)r*ABLK + blockIdx.x]            = cf[r];
    hist[(size_t)(NRANGE+r)*ABLK + blockIdx.x]   = cb[r];
  }
}

// ---------- generic 2-level scan over hist (M = 2*NRANGE*ABLK = 524288) ----------
__global__ void block_sum_kernel(const int* __restrict__ v, int* __restrict__ partial, int M) {
  __shared__ int sm[1024];
  int i = blockIdx.x*1024 + threadIdx.x;
  sm[threadIdx.x] = (i<M) ? v[i] : 0;
  __syncthreads();
  for (int s=512; s>0; s>>=1) {
    if (threadIdx.x < s) sm[threadIdx.x] += sm[threadIdx.x+s];
    __syncthreads();
  }
  if (threadIdx.x==0) partial[blockIdx.x] = sm[0];
}

__global__ void scan_partial_kernel(int* __restrict__ partial, int nb) {  // 512 threads
  __shared__ int sm[512];
  int t = threadIdx.x;
  int v = (t<nb) ? partial[t] : 0;
  int orig = v;
  sm[t] = v; __syncthreads();
  for (int off=1; off<512; off<<=1) {
    int a = (t>=off) ? sm[t-off] : 0;
    __syncthreads();
    v += a; sm[t] = v;
    __syncthreads();
  }
  if (t<nb) partial[t] = v - orig;   // exclusive block offsets
}

__global__ void scan_apply_kernel(const int* __restrict__ v, const int* __restrict__ partial,
                                  int* __restrict__ out, int M) {
  __shared__ int sm[1024];
  int i = blockIdx.x*1024 + threadIdx.x;
  int x = (i<M) ? v[i] : 0;
  int orig = x;
  sm[threadIdx.x] = x; __syncthreads();
  for (int off=1; off<1024; off<<=1) {
    int a = (threadIdx.x>=off) ? sm[threadIdx.x-off] : 0;
    __syncthreads();
    x += a; sm[threadIdx.x] = x;
    __syncthreads();
  }
  if (i<M) out[i] = x - orig + partial[blockIdx.x];   // exclusive scan
}

// ---------- A3: scatter (key,val) records into reserved segments, LDS-only atomics ----------
__global__ __launch_bounds__(256) void bin_scatter_kernel(const int* __restrict__ src,
                                                          const int* __restrict__ dst,
                                                          const int* __restrict__ offs,
                                                          int2* __restrict__ staged, int E) {
  __shared__ int ofF[NRANGE], ofB[NRANGE];
  for (int r=threadIdx.x; r<NRANGE; r+=256) {
    ofF[r] = offs[(size_t)r*ABLK + blockIdx.x];
    ofB[r] = offs[(size_t)(NRANGE+r)*ABLK + blockIdx.x];
  }
  __syncthreads();
  int epb = (E + ABLK-1)/ABLK;
  int lo = blockIdx.x*epb, hi = lo+epb; if (hi>E) hi=E;
  for (int e=lo+threadIdx.x; e<hi; e+=256) {
    int d = __builtin_nontemporal_load(&dst[e]);
    int s = __builtin_nontemporal_load(&src[e]);
    int pf = atomicAdd(&ofF[d>>RSHIFT], 1);
    staged[pf] = make_int2(d, s);              // fwd record: key=dst, val=src
    int pb = atomicAdd(&ofB[s>>RSHIFT], 1);
    staged[pb] = make_int2(s, d);              // bwd record: key=src, val=dst
  }
}

// ---------- B: per-range counting sort -> rp (coalesced) + col (L2-window scatter) ----------
__global__ __launch_bounds__(256) void range_fill_kernel(const int2* __restrict__ staged,
                                                         const int* __restrict__ offs,
                                                         int* __restrict__ rp_f, int* __restrict__ rp_b,
                                                         int* __restrict__ col_f, int* __restrict__ col_b,
                                                         int N, int E) {
  __shared__ int cnt[NPR], noff[NPR], sc[NPR];
  int lr = blockIdx.x;
  int d = lr >> 9, r = lr & (NRANGE-1);
  int start = offs[(size_t)lr*ABLK];
  int end   = (lr+1 < 2*NRANGE) ? offs[(size_t)(lr+1)*ABLK] : 2*E;
  int t = threadIdx.x;
  cnt[t] = 0; __syncthreads();
  for (int k=start+t; k<end; k+=256) {
    int key = staged[k].x;
    atomicAdd(&cnt[key & (NPR-1)], 1);
  }
  __syncthreads();
  int x = cnt[t]; sc[t] = x; __syncthreads();
  for (int off=1; off<NPR; off<<=1) {
    int a = (t>=off) ? sc[t-off] : 0;
    __syncthreads();
    x += a; sc[t] = x;
    __syncthreads();
  }
  noff[t] = x - cnt[t];
  __syncthreads();
  int base = d ? (start - E) : start;
  int node = (r << RSHIFT) + t;
  int* rp = d ? rp_b : rp_f;
  if (node < N)       rp[node] = base + noff[t];
  else if (node == N) rp[N]    = base + noff[t];
  cnt[t] = 0; __syncthreads();
  int* col = d ? col_b : col_f;
  for (int k=start+t; k<end; k+=256) {
    int2 rec = staged[k];
    int li = rec.x & (NPR-1);
    int rank = atomicAdd(&cnt[li], 1);
    col[base + noff[li] + rank] = rec.y;
  }
}

__global__ void cnt_kernel(const int* __restrict__ batch, int* __restrict__ cnt, int N) {
  __shared__ int hist[GG];
  if (threadIdx.x < GG) hist[threadIdx.x] = 0;
  __syncthreads();
  int i = blockIdx.x*blockDim.x + threadIdx.x;
  int stride = gridDim.x*blockDim.x;
  for (int n=i; n<N; n+=stride) atomicAdd(&hist[batch[n]], 1);
  __syncthreads();
  if (threadIdx.x < GG) atomicAdd(&cnt[threadIdx.x], hist[threadIdx.x]);
}

// ----------------- fp32 -> bf16 shadow -----------------
__global__ void tobf16_kernel(const float* __restrict__ in, ushort_t* __restrict__ out, int M) {
  int i = blockIdx.x*blockDim.x + threadIdx.x;
  int stride = gridDim.x*blockDim.x;
  for (int k=i; k<M; k+=stride) out[k] = f2bf(in[k]);
}

// ----------------- weight pack: [Wl;Wr] (K=128) -> MFMA B-fragment layout -----------------
__global__ void wpack_kernel(const float* __restrict__ Wl, const float* __restrict__ Wr,
                             ushort_t* __restrict__ Wb) {
  int l = blockIdx.x;
  const float* wl = Wl + (size_t)l*4096;
  const float* wr = Wr + (size_t)l*4096;
  ushort_t* out = Wb + (size_t)l*8192;
  for (int idx = threadIdx.x; idx < 8192; idx += 256) {
    int kb = idx >> 9, rem = idx & 511, col = rem >> 3, j = rem & 7;
    int k = kb*8 + j;
    float v = (k < 64) ? wl[(size_t)k*64+col] : wr[(size_t)(k-64)*64+col];
    out[idx] = f2bf(v);
  }
}

// ----------------- gather: one wave per node; 32-bit offsets + packed accumulate --------
__global__ __launch_bounds__(256) void gather_kernel(
    const ushort_t* __restrict__ hb,
    const int* __restrict__ rp_f, const int* __restrict__ col_f,
    const int* __restrict__ rp_b, const int* __restrict__ col_b,
    ushort_t* __restrict__ sbufb, int N)
{
  int w = (blockIdx.x*(blockDim.x>>6)) + (threadIdx.x>>6);   // node = global wave id
  if (w >= N) return;
  int lane = threadIdx.x & 63;
  int qt = lane >> 4;        // quarter 0..3
  int g  = lane & 15;        // feature quad: features 4g..4g+3
  const char* hbb = (const char*)hb;
  uint_t goff = (uint_t)g << 3;     // byte offset of this lane's quad within a row

  v2f a01={0.f,0.f}, a23={0.f,0.f}, c01={0.f,0.f}, c23={0.f,0.f};
  int degf, degb;

  {
    int s0 = rp_f[w], e0 = rp_f[w+1];
    degf = e0 - s0;
    for (int base=s0; base<e0; base+=64) {
      int m = e0-base; if (m>64) m=64;
      int jv = (lane<m) ? col_f[base+lane] : 0;
      int q=0;
      for (; 4*q+16 <= m; q+=4) {
        int j0=__shfl(jv,4*q+qt),    j1=__shfl(jv,4*q+4+qt);
        int j2=__shfl(jv,4*q+8+qt),  j3=__shfl(jv,4*q+12+qt);
        uint2 v0 = *(const uint2*)(hbb + ((((uint_t)j0)<<7) | goff));
        uint2 v1 = *(const uint2*)(hbb + ((((uint_t)j1)<<7) | goff));
        uint2 v2 = *(const uint2*)(hbb + ((((uint_t)j2)<<7) | goff));
        uint2 v3 = *(const uint2*)(hbb + ((((uint_t)j3)<<7) | goff));
        a01 += unpk(v0.x); a23 += unpk(v0.y);
        a01 += unpk(v1.x); a23 += unpk(v1.y);
        a01 += unpk(v2.x); a23 += unpk(v2.y);
        a01 += unpk(v3.x); a23 += unpk(v3.y);
      }
      for (; 4*q+qt < m; ++q) {
        int j=__shfl(jv,4*q+qt);
        uint2 v = *(const uint2*)(hbb + ((((uint_t)j)<<7) | goff));
        a01 += unpk(v.x); a23 += unpk(v.y);
      }
    }
  }
  {
    int s1 = rp_b[w], e1 = rp_b[w+1];
    degb = e1 - s1;
    for (int base=s1; base<e1; base+=64) {
      int m = e1-base; if (m>64) m=64;
      int jv = (lane<m) ? col_b[base+lane] : 0;
      int q=0;
      for (; 4*q+16 <= m; q+=4) {
        int j0=__shfl(jv,4*q+qt),    j1=__shfl(jv,4*q+4+qt);
        int j2=__shfl(jv,4*q+8+qt),  j3=__shfl(jv,4*q+12+qt);
        uint2 v0 = *(const uint2*)(hbb + ((((uint_t)j0)<<7) | goff));
        uint2 v1 = *(const uint2*)(hbb + ((((uint_t)j1)<<7) | goff));
        uint2 v2 = *(const uint2*)(hbb + ((((uint_t)j2)<<7) | goff));
        uint2 v3 = *(const uint2*)(hbb + ((((uint_t)j3)<<7) | goff));
        c01 += unpk(v0.x); c23 += unpk(v0.y);
        c01 += unpk(v1.x); c23 += unpk(v1.y);
        c01 += unpk(v2.x); c23 += unpk(v2.y);
        c01 += unpk(v3.x); c23 += unpk(v3.y);
      }
      for (; 4*q+qt < m; ++q) {
        int j=__shfl(jv,4*q+qt);
        uint2 v = *(const uint2*)(hbb + ((((uint_t)j)<<7) | goff));
        c01 += unpk(v.x); c23 += unpk(v.y);
      }
    }
  }

  float df = fmaxf((float)degf, 1.f);
  float db = fmaxf((float)degb, 1.f);
  float s0v = 0.5f*(a01.x/df + c01.x/db);
  float s1v = 0.5f*(a01.y/df + c01.y/db);
  float s2v = 0.5f*(a23.x/df + c23.x/db);
  float s3v = 0.5f*(a23.y/df + c23.y/db);
  s0v += __shfl_xor(s0v,16); s0v += __shfl_xor(s0v,32);
  s1v += __shfl_xor(s1v,16); s1v += __shfl_xor(s1v,32);
  s2v += __shfl_xor(s2v,16); s2v += __shfl_xor(s2v,32);
  s3v += __shfl_xor(s3v,16); s3v += __shfl_xor(s3v,32);
  if (qt==0) {
    uint_t p0 = (uint_t)f2bf(s0v) | ((uint_t)f2bf(s1v) << 16);
    uint_t p1 = (uint_t)f2bf(s2v) | ((uint_t)f2bf(s3v) << 16);
    *(uint2*)&((uint_t*)sbufb)[(size_t)w*32 + 2*g] = make_uint2(p0, p1);
  }
}

// --------- MFMA gemm + LDS-reduced stats + LDS-staged tb store ---------
// Block: 256 thr = 4 waves; wave w owns node strip [blk*64+16w, +16), all 4 col-tiles.
// Stats: LDS slot accumulation (<=8 graphs per 64-node window; fallback guard), then
// ~256 global atomics/block instead of 2048 (r15's 3.2M/dispatch was atomic-bound).
__global__ __launch_bounds__(256) void gemm_kernel(
    const ushort_t* __restrict__ hb, const ushort_t* __restrict__ sbufb,
    const ushort_t* __restrict__ Wb, const float* __restrict__ bias,
    const int* __restrict__ batch,
    ushort_t* __restrict__ tb, float* __restrict__ gsum, float* __restrict__ gsq, int N)
{
  __shared__ float lsum[8][DD];
  __shared__ float lsq[8][DD];
  __shared__ ushort_t tbs[64][DD];

  int wid = threadIdx.x >> 6;
  int lane = threadIdx.x & 63;
  int lrow = lane & 15;        // A-row within strip / C-col (feat) within tile
  int lk   = lane >> 4;        // k-subgroup
  int base = blockIdx.x*64;
  int strip = base + wid*16;

  int g0 = batch[(base < N) ? base : (N-1)];
  for (int i=threadIdx.x; i<8*DD; i+=256) { (&lsum[0][0])[i]=0.f; (&lsq[0][0])[i]=0.f; }

  int arow = strip + lrow; if (arow >= N) arow = N-1;   // clamp; OOB rows masked at store
  const bf16x8* sfrag = (const bf16x8*)(sbufb + (size_t)arow*DD);
  const bf16x8* hfrag = (const bf16x8*)(hb    + (size_t)arow*DD);
  bf16x8 a0 = sfrag[lk];       // s k 0..31
  bf16x8 a1 = sfrag[4+lk];     // s k 32..63
  bf16x8 a2 = hfrag[lk];       // h k 64..95
  bf16x8 a3 = hfrag[4+lk];     // h k 96..127

  const bf16x8* wbp = (const bf16x8*)Wb;   // unit index = kb*64 + col
  f32x4 acc[4];
  #pragma unroll
  for (int t=0; t<4; ++t) acc[t] = (f32x4){0.f,0.f,0.f,0.f};

  #pragma unroll
  for (int t=0; t<4; ++t) {
    int col = t*16 + lrow;
    bf16x8 b0 = wbp[(0*4+lk)*64 + col];
    bf16x8 b1 = wbp[(1*4+lk)*64 + col];
    bf16x8 b2 = wbp[(2*4+lk)*64 + col];
    bf16x8 b3 = wbp[(3*4+lk)*64 + col];
    acc[t] = __builtin_amdgcn_mfma_f32_16x16x32_bf16(a0, b0, acc[t], 0,0,0);
    acc[t] = __builtin_amdgcn_mfma_f32_16x16x32_bf16(a1, b1, acc[t], 0,0,0);
    acc[t] = __builtin_amdgcn_mfma_f32_16x16x32_bf16(a2, b2, acc[t], 0,0,0);
    acc[t] = __builtin_amdgcn_mfma_f32_16x16x32_bf16(a3, b3, acc[t], 0,0,0);
  }
  __syncthreads();    // lsum/lsq zero-init complete

  // C/D: node = strip + lk*4 + r, feat = t*16 + lrow  [verified mapping]
  int bt[4];
  #pragma unroll
  for (int r=0; r<4; ++r) {
    int node = strip + lk*4 + r;
    bt[r] = (node < N) ? batch[node] : -1;
  }
  #pragma unroll
  for (int t=0; t<4; ++t) {
    int feat = t*16 + lrow;
    float bv = bias[feat];
    int gcur = -1; float ga=0.f, qa=0.f;
    #pragma unroll
    for (int r=0; r<4; ++r) {
      if (bt[r] < 0) break;
      int node = strip + lk*4 + r;
      float v = acc[t][r] + bv;
      tbs[node-base][feat] = f2bf(v);
      if (bt[r] != gcur) {
        if (gcur >= 0) {
          int slot = gcur - g0;
          if (slot < 8) { atomicAdd(&lsum[slot][feat], ga); atomicAdd(&lsq[slot][feat], qa); }
          else { atomicAdd(&gsum[gcur*DD+feat], ga); atomicAdd(&gsq[gcur*DD+feat], qa); }
        }
        gcur = bt[r]; ga = 0.f; qa = 0.f;
      }
      ga += v; qa += v*v;
    }
    if (gcur >= 0) {
      int slot = gcur - g0;
      if (slot < 8) { atomicAdd(&lsum[slot][feat], ga); atomicAdd(&lsq[slot][feat], qa); }
      else { atomicAdd(&gsum[gcur*DD+feat], ga); atomicAdd(&gsq[gcur*DD+feat], qa); }
    }
  }
  __syncthreads();

  // flush per-block stats: ~2 slots typically
  int lastnode = base+63; if (lastnode >= N) lastnode = N-1;
  int nslots = batch[lastnode] - g0 + 1; if (nslots > 8) nslots = 8;
  for (int idx=threadIdx.x; idx < nslots*DD; idx += 256) {
    int s = idx >> 6, f = idx & 63;
    float vs = lsum[s][f], vq = lsq[s][f];
    if (vs != 0.f || vq != 0.f) {
      atomicAdd(&gsum[(g0+s)*DD+f], vs);
      atomicAdd(&gsq[(g0+s)*DD+f], vq);
    }
  }
  // vectorized tb store (16B per chunk)
  for (int c=threadIdx.x; c<512; c+=256) {
    int row = c >> 3, off = (c & 7)*8;
    int node = base + row;
    if (node < N) *(bf16x8*)&tb[(size_t)node*DD + off] = *(const bf16x8*)&tbs[row][off];
  }
}

// ---- GraphNorm (var from sums) + leaky + residual, bf16 state in-place; last fuses pool ----
__global__ void norm2_kernel(const ushort_t* __restrict__ tb,
                             const float* __restrict__ gsum, const float* __restrict__ gsq,
                             const int* __restrict__ cnt, const int* __restrict__ batch,
                             const float* __restrict__ gw, const float* __restrict__ gb,
                             const float* __restrict__ gms,
                             ushort_t* __restrict__ hb,
                             float* __restrict__ pout,
                             int resid, int last, int N)
{
  int wid = (blockIdx.x*blockDim.x + threadIdx.x) >> 6;
  int lane = threadIdx.x & 63;
  int base = wid*NRM_NPW;
  if (base >= N) return;
  float wv = gw[lane], bv = gb[lane], msv = gms[lane];
  float cms = msv*(2.f - msv);
  int gcur=-1; float rs=0.f, mean=0.f, pacc=0.f;
  int end = base+NRM_NPW; if (end>N) end=N;
  for (int node=base; node<end; ++node) {
    int g = batch[node];
    if (g!=gcur) {
      if (last && gcur>=0) atomicAdd(&pout[gcur*DD+lane], pacc);
      pacc = 0.f;
      float invc = 1.f/fmaxf((float)cnt[g],1.f);
      mean = gsum[g*DD+lane]*invc;
      float msq = gsq[g*DD+lane]*invc;
      float var = msq - cms*mean*mean;         // E[(t-ms*mean)^2]
      rs = rsqrtf(var + EPSV);
      gcur=g;
    }
    float u = bf2f(tb[(size_t)node*DD+lane]) - msv*mean;
    float y = wv*u*rs + bv;
    y = (y>=0.f) ? y : SLOPE*y;
    float hv = resid ? (bf2f(hb[(size_t)node*DD+lane]) + y) : y;
    if (last) {
      pacc += hv;                  // final h never re-read: pool only
    } else {
      hb[(size_t)node*DD+lane] = f2bf(hv);   // in-place: all layer-i readers done
    }
  }
  if (last && gcur>=0) atomicAdd(&pout[gcur*DD+lane], pacc);
}

__global__ void finalize_kernel(const float* __restrict__ pout, const int* __restrict__ cnt,
                                float* __restrict__ out)
{
  int i = blockIdx.x*blockDim.x + threadIdx.x;
  if (i < GG*DD) {
    float invc = 1.f/fmaxf((float)cnt[i>>6],1.f);
    out[i] = pout[i]*invc;
  }
}

extern "C" void kernel_launch(void* const* d_in, const int* in_sizes, int n_in,
                              void* d_out, int out_size, void* d_ws, size_t ws_size,
                              hipStream_t stream)
{
  const float* x    = (const float*)d_in[0];
  const int*  ei    = (const int*)d_in[1];
  const int*  batch = (const int*)d_in[2];
  const float* W_l  = (const float*)d_in[3];
  const float* W_r  = (const float*)d_in[4];
  const float* bias = (const float*)d_in[5];
  const float* gn_w = (const float*)d_in[6];
  const float* gn_b = (const float*)d_in[7];
  const float* gn_ms= (const float*)d_in[8];

  int N = in_sizes[2];
  int E = in_sizes[1]/2;
  int L = in_sizes[5]/DD;
  const int* src = ei;
  const int* dst = ei + E;

  // ---- workspace layout: zero-zone first (single memset) ----
  char* p = (char*)d_ws;
  int*   cnt   = (int*)p;   p += GG*4;
  float* gsum  = (float*)p; p += (size_t)L*GG*DD*4;
  float* gsq   = (float*)p; p += (size_t)L*GG*DD*4;
  float* pout  = (float*)p; p += GG*DD*4;
  size_t zeroBytes = (char*)p - (char*)d_ws;

  int2* staged = (int2*)p; p += (size_t)2*E*8;            // CSR build records (25.6MB)
  ushort_t* tb    = (ushort_t*)p; p += (size_t)N*DD*2;
  ushort_t* sbufb = (ushort_t*)p; p += (size_t)N*DD*2;
  ushort_t* hb    = (ushort_t*)p; p += (size_t)N*DD*2;
  ushort_t* wb    = (ushort_t*)p; p += (size_t)L*8192*2;  // packed MFMA weights
  int* rp_f    = (int*)p; p += (size_t)(N+1)*4;
  int* rp_b    = (int*)p; p += (size_t)(N+1)*4;
  int* col_f   = (int*)p; p += (size_t)E*4;
  int* col_b   = (int*)p; p += (size_t)E*4;
  int* hist    = (int*)p; p += (size_t)2*NRANGE*ABLK*4;   // 2MB
  int* offs    = (int*)p; p += (size_t)2*NRANGE*ABLK*4;   // 2MB
  int* partial = (int*)p; p += 512*4;

  hipMemsetAsync(d_ws, 0, zeroBytes, stream);

  const int M = 2*NRANGE*ABLK;  // 524288
  bin_count_kernel<<<ABLK, 256, 0, stream>>>(src, dst, hist, E);
  block_sum_kernel<<<(M+1023)/1024, 1024, 0, stream>>>(hist, partial, M);
  scan_partial_kernel<<<1, 512, 0, stream>>>(partial, (M+1023)/1024);
  scan_apply_kernel<<<(M+1023)/1024, 1024, 0, stream>>>(hist, partial, offs, M);
  bin_scatter_kernel<<<ABLK, 256, 0, stream>>>(src, dst, offs, staged, E);
  range_fill_kernel<<<2*NRANGE, 256, 0, stream>>>(staged, offs, rp_f, rp_b, col_f, col_b, N, E);

  cnt_kernel<<<391, 256, 0, stream>>>(batch, cnt, N);
  tobf16_kernel<<<2048, 256, 0, stream>>>(x, hb, N*DD);
  wpack_kernel<<<L, 256, 0, stream>>>(W_l, W_r, wb);

  int gthBlocks = (N + 3)/4;           // 4 waves (nodes) per 256-thread block
  int agBlocks = (N + 63)/64;          // 64 nodes per 256-thread MFMA block
  int nrmWaves = (N + NRM_NPW-1)/NRM_NPW;
  int nrmBlocks = (nrmWaves+3)/4;

  for (int i=0; i<L; ++i) {
    float* gsum_i = gsum + (size_t)i*GG*DD;
    float* gsq_i  = gsq  + (size_t)i*GG*DD;
    int last = (i==L-1) ? 1 : 0;
    gather_kernel<<<gthBlocks, 256, 0, stream>>>(hb, rp_f, col_f, rp_b, col_b, sbufb, N);
    gemm_kernel<<<agBlocks, 256, 0, stream>>>(hb, sbufb, wb + (size_t)i*8192,
                                              bias+(size_t)i*DD, batch, tb, gsum_i, gsq_i, N);
    norm2_kernel<<<nrmBlocks, 256, 0, stream>>>(tb, gsum_i, gsq_i, cnt, batch,
                                                gn_w+(size_t)i*DD, gn_b+(size_t)i*DD,
                                                gn_ms+(size_t)i*DD,
                                                hb, pout, (i>=2)?1:0, last, N);
  }
  finalize_kernel<<<16, 256, 0, stream>>>(pout, cnt, (float*)d_out);
}

// Round 18
// 671.128 us; speedup vs baseline: 1.5109x; 1.0559x over previous
//
#include <hip/hip_runtime.h>

#define DD 64
#define GG 64
#define EPSV 1e-5f
#define SLOPE 0.01f

#define NRM_NPW 16
#define NV_WN 32              // nodes per wave in vectorized norm2

// binned CSR build
#define NRANGE 512
#define RSHIFT 8              // 256 nodes per range (512*256 = 131072 >= N)
#define NPR 256
#define ABLK 512              // edge-chunk blocks in phases A1/A3

typedef unsigned short ushort_t;
typedef unsigned int uint_t;
typedef float v2f __attribute__((ext_vector_type(2)));
typedef __attribute__((ext_vector_type(8))) short bf16x8;
typedef __attribute__((ext_vector_type(4))) float f32x4;

__device__ __forceinline__ ushort_t f2bf(float f) {
  uint_t u = __float_as_uint(f);
  uint_t r = (u + 0x7fffu + ((u >> 16) & 1u)) >> 16;   // round-to-nearest-even
  return (ushort_t)r;
}
__device__ __forceinline__ float bf2f(ushort_t s) { return __uint_as_float(((uint_t)s) << 16); }
__device__ __forceinline__ v2f unpk(uint_t u) {      // {lo,hi} bf16 pair -> 2 floats
  v2f r;
  r.x = __uint_as_float(u << 16);
  r.y = __uint_as_float(u & 0xffff0000u);
  return r;
}

// ---------- A1: per-(block,range) histograms, both directions, LDS-only atomics ----------
__global__ __launch_bounds__(256) void bin_count_kernel(const int* __restrict__ src,
                                                        const int* __restrict__ dst,
                                                        int* __restrict__ hist, int E) {
  __shared__ int cf[NRANGE], cb[NRANGE];
  for (int i=threadIdx.x; i<NRANGE; i+=256) { cf[i]=0; cb[i]=0; }
  __syncthreads();
  int epb = (E + ABLK-1)/ABLK;
  int lo = blockIdx.x*epb, hi = lo+epb; if (hi>E) hi=E;
  for (int e=lo+threadIdx.x; e<hi; e+=256) {
    int d = __builtin_nontemporal_load(&dst[e]);
    int s = __builtin_nontemporal_load(&src[e]);
    atomicAdd(&cf[d>>RSHIFT], 1);
    atomicAdd(&cb[s>>RSHIFT], 1);
  }
  __syncthreads();
  for (int r=threadIdx.x; r<NRANGE; r+=256) {
    hist[(size_t)r*ABLK + blockIdx.x]            = cf[r];
    hist[(size_t)(NRANGE+r)*ABLK + blockIdx.x]   = cb[r];
  }
}

// ---------- generic 2-level scan over hist (M = 2*NRANGE*ABLK = 524288) ----------
__global__ void block_sum_kernel(const int* __restrict__ v, int* __restrict__ partial, int M) {
  __shared__ int sm[1024];
  int i = blockIdx.x*1024 + threadIdx.x;
  sm[threadIdx.x] = (i<M) ? v[i] : 0;
  __syncthreads();
  for (int s=512; s>0; s>>=1) {
    if (threadIdx.x < s) sm[threadIdx.x] += sm[threadIdx.x+s];
    __syncthreads();
  }
  if (threadIdx.x==0) partial[blockIdx.x] = sm[0];
}

__global__ void scan_partial_kernel(int* __restrict__ partial, int nb) {  // 512 threads
  __shared__ int sm[512];
  int t = threadIdx.x;
  int v = (t<nb) ? partial[t] : 0;
  int orig = v;
  sm[t] = v; __syncthreads();
  for (int off=1; off<512; off<<=1) {
    int a = (t>=off) ? sm[t-off] : 0;
    __syncthreads();
    v += a; sm[t] = v;
    __syncthreads();
  }
  if (t<nb) partial[t] = v - orig;   // exclusive block offsets
}

__global__ void scan_apply_kernel(const int* __restrict__ v, const int* __restrict__ partial,
                                  int* __restrict__ out, int M) {
  __shared__ int sm[1024];
  int i = blockIdx.x*1024 + threadIdx.x;
  int x = (i<M) ? v[i] : 0;
  int orig = x;
  sm[threadIdx.x] = x; __syncthreads();
  for (int off=1; off<1024; off<<=1) {
    int a = (threadIdx.x>=off) ? sm[threadIdx.x-off] : 0;
    __syncthreads();
    x += a; sm[threadIdx.x] = x;
    __syncthreads();
  }
  if (i<M) out[i] = x - orig + partial[blockIdx.x];   // exclusive scan
}

// ---------- A3: scatter packed records (val<<8 | local-key) into reserved segments ----------
__global__ __launch_bounds__(256) void bin_scatter_kernel(const int* __restrict__ src,
                                                          const int* __restrict__ dst,
                                                          const int* __restrict__ offs,
                                                          int* __restrict__ staged, int E) {
  __shared__ int ofF[NRANGE], ofB[NRANGE];
  for (int r=threadIdx.x; r<NRANGE; r+=256) {
    ofF[r] = offs[(size_t)r*ABLK + blockIdx.x];
    ofB[r] = offs[(size_t)(NRANGE+r)*ABLK + blockIdx.x];
  }
  __syncthreads();
  int epb = (E + ABLK-1)/ABLK;
  int lo = blockIdx.x*epb, hi = lo+epb; if (hi>E) hi=E;
  for (int e=lo+threadIdx.x; e<hi; e+=256) {
    int d = __builtin_nontemporal_load(&dst[e]);
    int s = __builtin_nontemporal_load(&src[e]);
    int pf = atomicAdd(&ofF[d>>RSHIFT], 1);
    staged[pf] = (s << 8) | (d & (NPR-1));     // fwd: key=dst(local), val=src
    int pb = atomicAdd(&ofB[s>>RSHIFT], 1);
    staged[pb] = (d << 8) | (s & (NPR-1));     // bwd: key=src(local), val=dst
  }
}

// ---------- B: per-range counting sort -> rp (coalesced) + col (L2-window scatter) ----------
__global__ __launch_bounds__(256) void range_fill_kernel(const int* __restrict__ staged,
                                                         const int* __restrict__ offs,
                                                         int* __restrict__ rp_f, int* __restrict__ rp_b,
                                                         int* __restrict__ col_f, int* __restrict__ col_b,
                                                         int N, int E) {
  __shared__ int cnt[NPR], noff[NPR], sc[NPR];
  int lr = blockIdx.x;
  int d = lr >> 9, r = lr & (NRANGE-1);
  int start = offs[(size_t)lr*ABLK];
  int end   = (lr+1 < 2*NRANGE) ? offs[(size_t)(lr+1)*ABLK] : 2*E;
  int t = threadIdx.x;
  cnt[t] = 0; __syncthreads();
  for (int k=start+t; k<end; k+=256) {
    atomicAdd(&cnt[staged[k] & (NPR-1)], 1);
  }
  __syncthreads();
  int x = cnt[t]; sc[t] = x; __syncthreads();
  for (int off=1; off<NPR; off<<=1) {
    int a = (t>=off) ? sc[t-off] : 0;
    __syncthreads();
    x += a; sc[t] = x;
    __syncthreads();
  }
  noff[t] = x - cnt[t];
  __syncthreads();
  int base = d ? (start - E) : start;
  int node = (r << RSHIFT) + t;
  int* rp = d ? rp_b : rp_f;
  if (node < N)       rp[node] = base + noff[t];
  else if (node == N) rp[N]    = base + noff[t];
  cnt[t] = 0; __syncthreads();
  int* col = d ? col_b : col_f;
  for (int k=start+t; k<end; k+=256) {
    int rec = staged[k];
    int li = rec & (NPR-1);
    int rank = atomicAdd(&cnt[li], 1);
    col[base + noff[li] + rank] = rec >> 8;
  }
}

__global__ void cnt_kernel(const int* __restrict__ batch, int* __restrict__ cnt, int N) {
  __shared__ int hist[GG];
  if (threadIdx.x < GG) hist[threadIdx.x] = 0;
  __syncthreads();
  int i = blockIdx.x*blockDim.x + threadIdx.x;
  int stride = gridDim.x*blockDim.x;
  for (int n=i; n<N; n+=stride) atomicAdd(&hist[batch[n]], 1);
  __syncthreads();
  if (threadIdx.x < GG) atomicAdd(&cnt[threadIdx.x], hist[threadIdx.x]);
}

// ----------------- fp32 -> bf16 shadow -----------------
__global__ void tobf16_kernel(const float* __restrict__ in, ushort_t* __restrict__ out, int M) {
  int i = blockIdx.x*blockDim.x + threadIdx.x;
  int stride = gridDim.x*blockDim.x;
  for (int k=i; k<M; k+=stride) out[k] = f2bf(in[k]);
}

// ----------------- weight pack: [Wl;Wr] (K=128) -> MFMA B-fragment layout -----------------
__global__ void wpack_kernel(const float* __restrict__ Wl, const float* __restrict__ Wr,
                             ushort_t* __restrict__ Wb) {
  int l = blockIdx.x;
  const float* wl = Wl + (size_t)l*4096;
  const float* wr = Wr + (size_t)l*4096;
  ushort_t* out = Wb + (size_t)l*8192;
  for (int idx = threadIdx.x; idx < 8192; idx += 256) {
    int kb = idx >> 9, rem = idx & 511, col = rem >> 3, j = rem & 7;
    int k = kb*8 + j;
    float v = (k < 64) ? wl[(size_t)k*64+col] : wr[(size_t)(k-64)*64+col];
    out[idx] = f2bf(v);
  }
}

// ----------------- gather: one wave per node; 32-bit offsets + packed accumulate --------
__global__ __launch_bounds__(256) void gather_kernel(
    const ushort_t* __restrict__ hb,
    const int* __restrict__ rp_f, const int* __restrict__ col_f,
    const int* __restrict__ rp_b, const int* __restrict__ col_b,
    ushort_t* __restrict__ sbufb, int N)
{
  int w = (blockIdx.x*(blockDim.x>>6)) + (threadIdx.x>>6);   // node = global wave id
  if (w >= N) return;
  int lane = threadIdx.x & 63;
  int qt = lane >> 4;        // quarter 0..3
  int g  = lane & 15;        // feature quad: features 4g..4g+3
  const char* hbb = (const char*)hb;
  uint_t goff = (uint_t)g << 3;     // byte offset of this lane's quad within a row

  v2f a01={0.f,0.f}, a23={0.f,0.f}, c01={0.f,0.f}, c23={0.f,0.f};
  int degf, degb;

  {
    int s0 = rp_f[w], e0 = rp_f[w+1];
    degf = e0 - s0;
    for (int base=s0; base<e0; base+=64) {
      int m = e0-base; if (m>64) m=64;
      int jv = (lane<m) ? col_f[base+lane] : 0;
      int q=0;
      for (; 4*q+16 <= m; q+=4) {
        int j0=__shfl(jv,4*q+qt),    j1=__shfl(jv,4*q+4+qt);
        int j2=__shfl(jv,4*q+8+qt),  j3=__shfl(jv,4*q+12+qt);
        uint2 v0 = *(const uint2*)(hbb + ((((uint_t)j0)<<7) | goff));
        uint2 v1 = *(const uint2*)(hbb + ((((uint_t)j1)<<7) | goff));
        uint2 v2 = *(const uint2*)(hbb + ((((uint_t)j2)<<7) | goff));
        uint2 v3 = *(const uint2*)(hbb + ((((uint_t)j3)<<7) | goff));
        a01 += unpk(v0.x); a23 += unpk(v0.y);
        a01 += unpk(v1.x); a23 += unpk(v1.y);
        a01 += unpk(v2.x); a23 += unpk(v2.y);
        a01 += unpk(v3.x); a23 += unpk(v3.y);
      }
      for (; 4*q+qt < m; ++q) {
        int j=__shfl(jv,4*q+qt);
        uint2 v = *(const uint2*)(hbb + ((((uint_t)j)<<7) | goff));
        a01 += unpk(v.x); a23 += unpk(v.y);
      }
    }
  }
  {
    int s1 = rp_b[w], e1 = rp_b[w+1];
    degb = e1 - s1;
    for (int base=s1; base<e1; base+=64) {
      int m = e1-base; if (m>64) m=64;
      int jv = (lane<m) ? col_b[base+lane] : 0;
      int q=0;
      for (; 4*q+16 <= m; q+=4) {
        int j0=__shfl(jv,4*q+qt),    j1=__shfl(jv,4*q+4+qt);
        int j2=__shfl(jv,4*q+8+qt),  j3=__shfl(jv,4*q+12+qt);
        uint2 v0 = *(const uint2*)(hbb + ((((uint_t)j0)<<7) | goff));
        uint2 v1 = *(const uint2*)(hbb + ((((uint_t)j1)<<7) | goff));
        uint2 v2 = *(const uint2*)(hbb + ((((uint_t)j2)<<7) | goff));
        uint2 v3 = *(const uint2*)(hbb + ((((uint_t)j3)<<7) | goff));
        c01 += unpk(v0.x); c23 += unpk(v0.y);
        c01 += unpk(v1.x); c23 += unpk(v1.y);
        c01 += unpk(v2.x); c23 += unpk(v2.y);
        c01 += unpk(v3.x); c23 += unpk(v3.y);
      }
      for (; 4*q+qt < m; ++q) {
        int j=__shfl(jv,4*q+qt);
        uint2 v = *(const uint2*)(hbb + ((((uint_t)j)<<7) | goff));
        c01 += unpk(v.x); c23 += unpk(v.y);
      }
    }
  }

  float df = fmaxf((float)degf, 1.f);
  float db = fmaxf((float)degb, 1.f);
  float s0v = 0.5f*(a01.x/df + c01.x/db);
  float s1v = 0.5f*(a01.y/df + c01.y/db);
  float s2v = 0.5f*(a23.x/df + c23.x/db);
  float s3v = 0.5f*(a23.y/df + c23.y/db);
  s0v += __shfl_xor(s0v,16); s0v += __shfl_xor(s0v,32);
  s1v += __shfl_xor(s1v,16); s1v += __shfl_xor(s1v,32);
  s2v += __shfl_xor(s2v,16); s2v += __shfl_xor(s2v,32);
  s3v += __shfl_xor(s3v,16); s3v += __shfl_xor(s3v,32);
  if (qt==0) {
    uint_t p0 = (uint_t)f2bf(s0v) | ((uint_t)f2bf(s1v) << 16);
    uint_t p1 = (uint_t)f2bf(s2v) | ((uint_t)f2bf(s3v) << 16);
    *(uint2*)&((uint_t*)sbufb)[(size_t)w*32 + 2*g] = make_uint2(p0, p1);
  }
}

// --------- MFMA gemm + LDS-reduced stats + LDS-staged tb store ---------
__global__ __launch_bounds__(256) void gemm_kernel(
    const ushort_t* __restrict__ hb, const ushort_t* __restrict__ sbufb,
    const ushort_t* __restrict__ Wb, const float* __restrict__ bias,
    const int* __restrict__ batch,
    ushort_t* __restrict__ tb, float* __restrict__ gsum, float* __restrict__ gsq, int N)
{
  __shared__ float lsum[8][DD];
  __shared__ float lsq[8][DD];
  __shared__ ushort_t tbs[64][DD];

  int wid = threadIdx.x >> 6;
  int lane = threadIdx.x & 63;
  int lrow = lane & 15;        // A-row within strip / C-col (feat) within tile
  int lk   = lane >> 4;        // k-subgroup
  int base = blockIdx.x*64;
  int strip = base + wid*16;

  int g0 = batch[(base < N) ? base : (N-1)];
  for (int i=threadIdx.x; i<8*DD; i+=256) { (&lsum[0][0])[i]=0.f; (&lsq[0][0])[i]=0.f; }

  int arow = strip + lrow; if (arow >= N) arow = N-1;   // clamp; OOB rows masked at store
  const bf16x8* sfrag = (const bf16x8*)(sbufb + (size_t)arow*DD);
  const bf16x8* hfrag = (const bf16x8*)(hb    + (size_t)arow*DD);
  bf16x8 a0 = sfrag[lk];       // s k 0..31
  bf16x8 a1 = sfrag[4+lk];     // s k 32..63
  bf16x8 a2 = hfrag[lk];       // h k 64..95
  bf16x8 a3 = hfrag[4+lk];     // h k 96..127

  const bf16x8* wbp = (const bf16x8*)Wb;   // unit index = kb*64 + col
  f32x4 acc[4];
  #pragma unroll
  for (int t=0; t<4; ++t) acc[t] = (f32x4){0.f,0.f,0.f,0.f};

  #pragma unroll
  for (int t=0; t<4; ++t) {
    int col = t*16 + lrow;
    bf16x8 b0 = wbp[(0*4+lk)*64 + col];
    bf16x8 b1 = wbp[(1*4+lk)*64 + col];
    bf16x8 b2 = wbp[(2*4+lk)*64 + col];
    bf16x8 b3 = wbp[(3*4+lk)*64 + col];
    acc[t] = __builtin_amdgcn_mfma_f32_16x16x32_bf16(a0, b0, acc[t], 0,0,0);
    acc[t] = __builtin_amdgcn_mfma_f32_16x16x32_bf16(a1, b1, acc[t], 0,0,0);
    acc[t] = __builtin_amdgcn_mfma_f32_16x16x32_bf16(a2, b2, acc[t], 0,0,0);
    acc[t] = __builtin_amdgcn_mfma_f32_16x16x32_bf16(a3, b3, acc[t], 0,0,0);
  }
  __syncthreads();    // lsum/lsq zero-init complete

  // C/D: node = strip + lk*4 + r, feat = t*16 + lrow  [verified mapping]
  int bt[4];
  #pragma unroll
  for (int r=0; r<4; ++r) {
    int node = strip + lk*4 + r;
    bt[r] = (node < N) ? batch[node] : -1;
  }
  #pragma unroll
  for (int t=0; t<4; ++t) {
    int feat = t*16 + lrow;
    float bv = bias[feat];
    int gcur = -1; float ga=0.f, qa=0.f;
    #pragma unroll
    for (int r=0; r<4; ++r) {
      if (bt[r] < 0) break;
      int node = strip + lk*4 + r;
      float v = acc[t][r] + bv;
      tbs[node-base][feat] = f2bf(v);
      if (bt[r] != gcur) {
        if (gcur >= 0) {
          int slot = gcur - g0;
          if (slot < 8) { atomicAdd(&lsum[slot][feat], ga); atomicAdd(&lsq[slot][feat], qa); }
          else { atomicAdd(&gsum[gcur*DD+feat], ga); atomicAdd(&gsq[gcur*DD+feat], qa); }
        }
        gcur = bt[r]; ga = 0.f; qa = 0.f;
      }
      ga += v; qa += v*v;
    }
    if (gcur >= 0) {
      int slot = gcur - g0;
      if (slot < 8) { atomicAdd(&lsum[slot][feat], ga); atomicAdd(&lsq[slot][feat], qa); }
      else { atomicAdd(&gsum[gcur*DD+feat], ga); atomicAdd(&gsq[gcur*DD+feat], qa); }
    }
  }
  __syncthreads();

  // flush per-block stats: ~2 slots typically
  int lastnode = base+63; if (lastnode >= N) lastnode = N-1;
  int nslots = batch[lastnode] - g0 + 1; if (nslots > 8) nslots = 8;
  for (int idx=threadIdx.x; idx < nslots*DD; idx += 256) {
    int s = idx >> 6, f = idx & 63;
    float vs = lsum[s][f], vq = lsq[s][f];
    if (vs != 0.f || vq != 0.f) {
      atomicAdd(&gsum[(g0+s)*DD+f], vs);
      atomicAdd(&gsq[(g0+s)*DD+f], vq);
    }
  }
  // vectorized tb store (16B per chunk)
  for (int c=threadIdx.x; c<512; c+=256) {
    int row = c >> 3, off = (c & 7)*8;
    int node = base + row;
    if (node < N) *(bf16x8*)&tb[(size_t)node*DD + off] = *(const bf16x8*)&tbs[row][off];
  }
}

// ---- vectorized GraphNorm (non-last layers): lane = (node-of-8, feat-octet), 16B chunks ----
__global__ __launch_bounds__(256) void norm2v_kernel(
    const ushort_t* __restrict__ tb,
    const float* __restrict__ gsum, const float* __restrict__ gsq,
    const int* __restrict__ cnt, const int* __restrict__ batch,
    const float* __restrict__ gw, const float* __restrict__ gb,
    const float* __restrict__ gms,
    ushort_t* __restrict__ hb, int resid, int N)
{
  int wv_id = (blockIdx.x*blockDim.x + threadIdx.x) >> 6;
  int lane = threadIdx.x & 63;
  int oct = lane & 7;          // feature octet (feats oct*8 .. +7)
  int no  = lane >> 3;         // node within 8-group
  int base = wv_id * NV_WN;
  if (base >= N) return;
  float wvv[8], bvv[8], msv[8];
  #pragma unroll
  for (int j=0;j<8;++j){ int f=oct*8+j; wvv[j]=gw[f]; bvv[j]=gb[f]; msv[j]=gms[f]; }
  int gcur=-1; float mean[8], rs[8];
  int end = base + NV_WN; if (end > N) end = N;
  for (int nb=base+no; nb<end; nb+=8) {
    int g = batch[nb];
    if (g != gcur) {
      float invc = 1.f/fmaxf((float)cnt[g],1.f);
      #pragma unroll
      for (int j=0;j<8;++j){
        int f = oct*8+j;
        float mn = gsum[g*DD+f]*invc;
        float mq = gsq[g*DD+f]*invc;
        float var = mq - msv[j]*(2.f-msv[j])*mn*mn;
        mean[j]=mn; rs[j]=rsqrtf(var+EPSV);
      }
      gcur=g;
    }
    bf16x8 tv = *(const bf16x8*)&tb[(size_t)nb*DD + oct*8];
    bf16x8 hv8 = *(const bf16x8*)&hb[(size_t)nb*DD + oct*8];
    bf16x8 outv;
    #pragma unroll
    for (int j=0;j<8;++j){
      float u = bf2f((ushort_t)tv[j]) - msv[j]*mean[j];
      float y = wvv[j]*u*rs[j] + bvv[j];
      y = (y>=0.f) ? y : SLOPE*y;
      float hvv = resid ? (bf2f((ushort_t)hv8[j]) + y) : y;
      outv[j] = (short)f2bf(hvv);
    }
    *(bf16x8*)&hb[(size_t)nb*DD + oct*8] = outv;
  }
}

// ---- last-layer GraphNorm (scalar, pool fused; runs once) ----
__global__ void norm2_last_kernel(const ushort_t* __restrict__ tb,
                             const float* __restrict__ gsum, const float* __restrict__ gsq,
                             const int* __restrict__ cnt, const int* __restrict__ batch,
                             const float* __restrict__ gw, const float* __restrict__ gb,
                             const float* __restrict__ gms,
                             const ushort_t* __restrict__ hb,
                             float* __restrict__ pout, int N)
{
  int wid = (blockIdx.x*blockDim.x + threadIdx.x) >> 6;
  int lane = threadIdx.x & 63;
  int base = wid*NRM_NPW;
  if (base >= N) return;
  float wv = gw[lane], bv = gb[lane], msv = gms[lane];
  float cms = msv*(2.f - msv);
  int gcur=-1; float rs=0.f, mean=0.f, pacc=0.f;
  int end = base+NRM_NPW; if (end>N) end=N;
  for (int node=base; node<end; ++node) {
    int g = batch[node];
    if (g!=gcur) {
      if (gcur>=0) atomicAdd(&pout[gcur*DD+lane], pacc);
      pacc = 0.f;
      float invc = 1.f/fmaxf((float)cnt[g],1.f);
      mean = gsum[g*DD+lane]*invc;
      float msq = gsq[g*DD+lane]*invc;
      float var = msq - cms*mean*mean;
      rs = rsqrtf(var + EPSV);
      gcur=g;
    }
    float u = bf2f(tb[(size_t)node*DD+lane]) - msv*mean;
    float y = wv*u*rs + bv;
    y = (y>=0.f) ? y : SLOPE*y;
    pacc += bf2f(hb[(size_t)node*DD+lane]) + y;   // resid always true on last layer (L>2)
  }
  if (gcur>=0) atomicAdd(&pout[gcur*DD+lane], pacc);
}

__global__ void finalize_kernel(const float* __restrict__ pout, const int* __restrict__ cnt,
                                float* __restrict__ out)
{
  int i = blockIdx.x*blockDim.x + threadIdx.x;
  if (i < GG*DD) {
    float invc = 1.f/fmaxf((float)cnt[i>>6],1.f);
    out[i] = pout[i]*invc;
  }
}

extern "C" void kernel_launch(void* const* d_in, const int* in_sizes, int n_in,
                              void* d_out, int out_size, void* d_ws, size_t ws_size,
                              hipStream_t stream)
{
  const float* x    = (const float*)d_in[0];
  const int*  ei    = (const int*)d_in[1];
  const int*  batch = (const int*)d_in[2];
  const float* W_l  = (const float*)d_in[3];
  const float* W_r  = (const float*)d_in[4];
  const float* bias = (const float*)d_in[5];
  const float* gn_w = (const float*)d_in[6];
  const float* gn_b = (const float*)d_in[7];
  const float* gn_ms= (const float*)d_in[8];

  int N = in_sizes[2];
  int E = in_sizes[1]/2;
  int L = in_sizes[5]/DD;
  const int* src = ei;
  const int* dst = ei + E;

  // ---- workspace layout: zero-zone first (single memset) ----
  char* p = (char*)d_ws;
  int*   cnt   = (int*)p;   p += GG*4;
  float* gsum  = (float*)p; p += (size_t)L*GG*DD*4;
  float* gsq   = (float*)p; p += (size_t)L*GG*DD*4;
  float* pout  = (float*)p; p += GG*DD*4;
  size_t zeroBytes = (char*)p - (char*)d_ws;

  int* staged  = (int*)p; p += (size_t)2*E*4;             // packed CSR records (12.8MB)
  ushort_t* tb    = (ushort_t*)p; p += (size_t)N*DD*2;
  ushort_t* sbufb = (ushort_t*)p; p += (size_t)N*DD*2;
  ushort_t* hb    = (ushort_t*)p; p += (size_t)N*DD*2;
  ushort_t* wb    = (ushort_t*)p; p += (size_t)L*8192*2;  // packed MFMA weights
  int* rp_f    = (int*)p; p += (size_t)(N+1)*4;
  int* rp_b    = (int*)p; p += (size_t)(N+1)*4;
  int* col_f   = (int*)p; p += (size_t)E*4;
  int* col_b   = (int*)p; p += (size_t)E*4;
  int* hist    = (int*)p; p += (size_t)2*NRANGE*ABLK*4;   // 2MB
  int* offs    = (int*)p; p += (size_t)2*NRANGE*ABLK*4;   // 2MB
  int* partial = (int*)p; p += 512*4;

  hipMemsetAsync(d_ws, 0, zeroBytes, stream);

  const int M = 2*NRANGE*ABLK;  // 524288
  bin_count_kernel<<<ABLK, 256, 0, stream>>>(src, dst, hist, E);
  block_sum_kernel<<<(M+1023)/1024, 1024, 0, stream>>>(hist, partial, M);
  scan_partial_kernel<<<1, 512, 0, stream>>>(partial, (M+1023)/1024);
  scan_apply_kernel<<<(M+1023)/1024, 1024, 0, stream>>>(hist, partial, offs, M);
  bin_scatter_kernel<<<ABLK, 256, 0, stream>>>(src, dst, offs, staged, E);
  range_fill_kernel<<<2*NRANGE, 256, 0, stream>>>(staged, offs, rp_f, rp_b, col_f, col_b, N, E);

  cnt_kernel<<<391, 256, 0, stream>>>(batch, cnt, N);
  tobf16_kernel<<<2048, 256, 0, stream>>>(x, hb, N*DD);
  wpack_kernel<<<L, 256, 0, stream>>>(W_l, W_r, wb);

  int gthBlocks = (N + 3)/4;           // 4 waves (nodes) per 256-thread block
  int agBlocks = (N + 63)/64;          // 64 nodes per 256-thread MFMA block
  int nvWaves = (N + NV_WN-1)/NV_WN;
  int nvBlocks = (nvWaves+3)/4;
  int nrmWaves = (N + NRM_NPW-1)/NRM_NPW;
  int nrmBlocks = (nrmWaves+3)/4;

  for (int i=0; i<L; ++i) {
    float* gsum_i = gsum + (size_t)i*GG*DD;
    float* gsq_i  = gsq  + (size_t)i*GG*DD;
    gather_kernel<<<gthBlocks, 256, 0, stream>>>(hb, rp_f, col_f, rp_b, col_b, sbufb, N);
    gemm_kernel<<<agBlocks, 256, 0, stream>>>(hb, sbufb, wb + (size_t)i*8192,
                                              bias+(size_t)i*DD, batch, tb, gsum_i, gsq_i, N);
    if (i < L-1) {
      norm2v_kernel<<<nvBlocks, 256, 0, stream>>>(tb, gsum_i, gsq_i, cnt, batch,
                                                  gn_w+(size_t)i*DD, gn_b+(size_t)i*DD,
                                                  gn_ms+(size_t)i*DD, hb, (i>=2)?1:0, N);
    } else {
      norm2_last_kernel<<<nrmBlocks, 256, 0, stream>>>(tb, gsum_i, gsq_i, cnt, batch,
                                                       gn_w+(size_t)i*DD, gn_b+(size_t)i*DD,
                                                       gn_ms+(size_t)i*DD, hb, pout, N);
    }
  }
  finalize_kernel<<<16, 256, 0, stream>>>(pout, cnt, (float*)d_out);
}

// Round 19
// 647.796 us; speedup vs baseline: 1.5653x; 1.0360x over previous
//
#include <hip/hip_runtime.h>

#define DD 64
#define GG 64
#define EPSV 1e-5f
#define SLOPE 0.01f

#define NRM_NPW 16
#define NV_WN 32              // nodes per wave in vectorized norm2

// binned CSR build
#define NRANGE 512
#define RSHIFT 8              // 256 nodes per range (512*256 = 131072 >= N)
#define NPR 256
#define ABLK 512              // edge-chunk blocks in phases A1/A3

typedef unsigned short ushort_t;
typedef unsigned int uint_t;
typedef float v2f __attribute__((ext_vector_type(2)));
typedef __attribute__((ext_vector_type(8))) short bf16x8;
typedef __attribute__((ext_vector_type(4))) float f32x4;

__device__ __forceinline__ ushort_t f2bf(float f) {
  uint_t u = __float_as_uint(f);
  uint_t r = (u + 0x7fffu + ((u >> 16) & 1u)) >> 16;   // round-to-nearest-even
  return (ushort_t)r;
}
__device__ __forceinline__ float bf2f(ushort_t s) { return __uint_as_float(((uint_t)s) << 16); }
__device__ __forceinline__ v2f unpk(uint_t u) {      // {lo,hi} bf16 pair -> 2 floats
  v2f r;
  r.x = __uint_as_float(u << 16);
  r.y = __uint_as_float(u & 0xffff0000u);
  return r;
}

// ---------- A1: per-(block,range) histograms, both directions, LDS-only atomics ----------
__global__ __launch_bounds__(256) void bin_count_kernel(const int* __restrict__ src,
                                                        const int* __restrict__ dst,
                                                        int* __restrict__ hist, int E) {
  __shared__ int cf[NRANGE], cb[NRANGE];
  for (int i=threadIdx.x; i<NRANGE; i+=256) { cf[i]=0; cb[i]=0; }
  __syncthreads();
  int epb = (E + ABLK-1)/ABLK;
  int lo = blockIdx.x*epb, hi = lo+epb; if (hi>E) hi=E;
  for (int e=lo+threadIdx.x; e<hi; e+=256) {
    int d = __builtin_nontemporal_load(&dst[e]);
    int s = __builtin_nontemporal_load(&src[e]);
    atomicAdd(&cf[d>>RSHIFT], 1);
    atomicAdd(&cb[s>>RSHIFT], 1);
  }
  __syncthreads();
  for (int r=threadIdx.x; r<NRANGE; r+=256) {
    hist[(size_t)r*ABLK + blockIdx.x]            = cf[r];
    hist[(size_t)(NRANGE+r)*ABLK + blockIdx.x]   = cb[r];
  }
}

// ---------- generic 2-level scan over hist (M = 2*NRANGE*ABLK = 524288) ----------
__global__ void block_sum_kernel(const int* __restrict__ v, int* __restrict__ partial, int M) {
  __shared__ int sm[1024];
  int i = blockIdx.x*1024 + threadIdx.x;
  sm[threadIdx.x] = (i<M) ? v[i] : 0;
  __syncthreads();
  for (int s=512; s>0; s>>=1) {
    if (threadIdx.x < s) sm[threadIdx.x] += sm[threadIdx.x+s];
    __syncthreads();
  }
  if (threadIdx.x==0) partial[blockIdx.x] = sm[0];
}

__global__ void scan_partial_kernel(int* __restrict__ partial, int nb) {  // 512 threads
  __shared__ int sm[512];
  int t = threadIdx.x;
  int v = (t<nb) ? partial[t] : 0;
  int orig = v;
  sm[t] = v; __syncthreads();
  for (int off=1; off<512; off<<=1) {
    int a = (t>=off) ? sm[t-off] : 0;
    __syncthreads();
    v += a; sm[t] = v;
    __syncthreads();
  }
  if (t<nb) partial[t] = v - orig;   // exclusive block offsets
}

__global__ void scan_apply_kernel(const int* __restrict__ v, const int* __restrict__ partial,
                                  int* __restrict__ out, int M) {
  __shared__ int sm[1024];
  int i = blockIdx.x*1024 + threadIdx.x;
  int x = (i<M) ? v[i] : 0;
  int orig = x;
  sm[threadIdx.x] = x; __syncthreads();
  for (int off=1; off<1024; off<<=1) {
    int a = (threadIdx.x>=off) ? sm[threadIdx.x-off] : 0;
    __syncthreads();
    x += a; sm[threadIdx.x] = x;
    __syncthreads();
  }
  if (i<M) out[i] = x - orig + partial[blockIdx.x];   // exclusive scan
}

// ---------- A3: scatter packed records (val<<8 | local-key) into reserved segments ----------
__global__ __launch_bounds__(256) void bin_scatter_kernel(const int* __restrict__ src,
                                                          const int* __restrict__ dst,
                                                          const int* __restrict__ offs,
                                                          int* __restrict__ staged, int E) {
  __shared__ int ofF[NRANGE], ofB[NRANGE];
  for (int r=threadIdx.x; r<NRANGE; r+=256) {
    ofF[r] = offs[(size_t)r*ABLK + blockIdx.x];
    ofB[r] = offs[(size_t)(NRANGE+r)*ABLK + blockIdx.x];
  }
  __syncthreads();
  int epb = (E + ABLK-1)/ABLK;
  int lo = blockIdx.x*epb, hi = lo+epb; if (hi>E) hi=E;
  for (int e=lo+threadIdx.x; e<hi; e+=256) {
    int d = __builtin_nontemporal_load(&dst[e]);
    int s = __builtin_nontemporal_load(&src[e]);
    int pf = atomicAdd(&ofF[d>>RSHIFT], 1);
    staged[pf] = (s << 8) | (d & (NPR-1));     // fwd: key=dst(local), val=src
    int pb = atomicAdd(&ofB[s>>RSHIFT], 1);
    staged[pb] = (d << 8) | (s & (NPR-1));     // bwd: key=src(local), val=dst
  }
}

// ---------- B: per-range counting sort -> rp (coalesced) + col (L2-window scatter) ----------
__global__ __launch_bounds__(256) void range_fill_kernel(const int* __restrict__ staged,
                                                         const int* __restrict__ offs,
                                                         int* __restrict__ rp_f, int* __restrict__ rp_b,
                                                         int* __restrict__ col_f, int* __restrict__ col_b,
                                                         int N, int E) {
  __shared__ int cnt[NPR], noff[NPR], sc[NPR];
  int lr = blockIdx.x;
  int d = lr >> 9, r = lr & (NRANGE-1);
  int start = offs[(size_t)lr*ABLK];
  int end   = (lr+1 < 2*NRANGE) ? offs[(size_t)(lr+1)*ABLK] : 2*E;
  int t = threadIdx.x;
  cnt[t] = 0; __syncthreads();
  for (int k=start+t; k<end; k+=256) {
    atomicAdd(&cnt[staged[k] & (NPR-1)], 1);
  }
  __syncthreads();
  int x = cnt[t]; sc[t] = x; __syncthreads();
  for (int off=1; off<NPR; off<<=1) {
    int a = (t>=off) ? sc[t-off] : 0;
    __syncthreads();
    x += a; sc[t] = x;
    __syncthreads();
  }
  noff[t] = x - cnt[t];
  __syncthreads();
  int base = d ? (start - E) : start;
  int node = (r << RSHIFT) + t;
  int* rp = d ? rp_b : rp_f;
  if (node < N)       rp[node] = base + noff[t];
  else if (node == N) rp[N]    = base + noff[t];
  cnt[t] = 0; __syncthreads();
  int* col = d ? col_b : col_f;
  for (int k=start+t; k<end; k+=256) {
    int rec = staged[k];
    int li = rec & (NPR-1);
    int rank = atomicAdd(&cnt[li], 1);
    col[base + noff[li] + rank] = rec >> 8;
  }
}

__global__ void cnt_kernel(const int* __restrict__ batch, int* __restrict__ cnt, int N) {
  __shared__ int hist[GG];
  if (threadIdx.x < GG) hist[threadIdx.x] = 0;
  __syncthreads();
  int i = blockIdx.x*blockDim.x + threadIdx.x;
  int stride = gridDim.x*blockDim.x;
  for (int n=i; n<N; n+=stride) atomicAdd(&hist[batch[n]], 1);
  __syncthreads();
  if (threadIdx.x < GG) atomicAdd(&cnt[threadIdx.x], hist[threadIdx.x]);
}

// ----------------- fp32 -> bf16 shadow -----------------
__global__ void tobf16_kernel(const float* __restrict__ in, ushort_t* __restrict__ out, int M) {
  int i = blockIdx.x*blockDim.x + threadIdx.x;
  int stride = gridDim.x*blockDim.x;
  for (int k=i; k<M; k+=stride) out[k] = f2bf(in[k]);
}

// ----------------- weight pack: [Wl;Wr] (K=128) -> MFMA B-fragment layout -----------------
__global__ void wpack_kernel(const float* __restrict__ Wl, const float* __restrict__ Wr,
                             ushort_t* __restrict__ Wb) {
  int l = blockIdx.x;
  const float* wl = Wl + (size_t)l*4096;
  const float* wr = Wr + (size_t)l*4096;
  ushort_t* out = Wb + (size_t)l*8192;
  for (int idx = threadIdx.x; idx < 8192; idx += 256) {
    int kb = idx >> 9, rem = idx & 511, col = rem >> 3, j = rem & 7;
    int k = kb*8 + j;
    float v = (k < 64) ? wl[(size_t)k*64+col] : wr[(size_t)(k-64)*64+col];
    out[idx] = f2bf(v);
  }
}

// ======== FUSED gather + MFMA gemm + stats: block = 256 thr = 4 waves = 16 nodes ========
// Phase 1: wave w gathers nodes base+4w..+3 (same per-node loop as before), s-rows ->
//          LDS bf16 [16][72] (72-ushort stride: conflict-free b128 reads).
// Phase 2: wave w computes col-tile w (feats 16w..16w+15) for all 16 nodes:
//          A = LDS s (K 0..63) + global hb (K 64..127), B = packed Wb; 4 MFMAs.
//          Epilogue: LDS-slot stats + LDS-staged tb, as r16.
// Rationale: gemm VALU/MFMA work of some blocks overlaps other blocks' miss-bound
// gather phase; kills sbufb round-trip (25MB/layer) + 5 launches.
__global__ __launch_bounds__(256) void gg_kernel(
    const ushort_t* __restrict__ hb,
    const int* __restrict__ rp_f, const int* __restrict__ col_f,
    const int* __restrict__ rp_b, const int* __restrict__ col_b,
    const ushort_t* __restrict__ Wb, const float* __restrict__ bias,
    const int* __restrict__ batch,
    ushort_t* __restrict__ tb, float* __restrict__ gsum, float* __restrict__ gsq, int N)
{
  __shared__ ushort_t srow[16][72];      // padded: row stride 144B = 9*16B
  __shared__ float lsum[4][DD];
  __shared__ float lsq[4][DD];
  __shared__ ushort_t tbs[16][DD];

  int wid = threadIdx.x >> 6;
  int lane = threadIdx.x & 63;
  int base = blockIdx.x*16;

  for (int i=threadIdx.x; i<4*DD; i+=256) { (&lsum[0][0])[i]=0.f; (&lsq[0][0])[i]=0.f; }

  // ---------------- phase 1: gather 4 nodes per wave ----------------
  {
    int qt = lane >> 4;
    int g  = lane & 15;
    const char* hbb = (const char*)hb;
    uint_t goff = (uint_t)g << 3;

    for (int nn=0; nn<4; ++nn) {
      int w = base + wid*4 + nn;
      v2f a01={0.f,0.f}, a23={0.f,0.f}, c01={0.f,0.f}, c23={0.f,0.f};
      int degf=0, degb=0;
      if (w < N) {
        {
          int s0 = rp_f[w], e0 = rp_f[w+1];
          degf = e0 - s0;
          for (int bse=s0; bse<e0; bse+=64) {
            int m = e0-bse; if (m>64) m=64;
            int jv = (lane<m) ? col_f[bse+lane] : 0;
            int q=0;
            for (; 4*q+16 <= m; q+=4) {
              int j0=__shfl(jv,4*q+qt),    j1=__shfl(jv,4*q+4+qt);
              int j2=__shfl(jv,4*q+8+qt),  j3=__shfl(jv,4*q+12+qt);
              uint2 v0 = *(const uint2*)(hbb + ((((uint_t)j0)<<7) | goff));
              uint2 v1 = *(const uint2*)(hbb + ((((uint_t)j1)<<7) | goff));
              uint2 v2 = *(const uint2*)(hbb + ((((uint_t)j2)<<7) | goff));
              uint2 v3 = *(const uint2*)(hbb + ((((uint_t)j3)<<7) | goff));
              a01 += unpk(v0.x); a23 += unpk(v0.y);
              a01 += unpk(v1.x); a23 += unpk(v1.y);
              a01 += unpk(v2.x); a23 += unpk(v2.y);
              a01 += unpk(v3.x); a23 += unpk(v3.y);
            }
            for (; 4*q+qt < m; ++q) {
              int j=__shfl(jv,4*q+qt);
              uint2 v = *(const uint2*)(hbb + ((((uint_t)j)<<7) | goff));
              a01 += unpk(v.x); a23 += unpk(v.y);
            }
          }
        }
        {
          int s1 = rp_b[w], e1 = rp_b[w+1];
          degb = e1 - s1;
          for (int bse=s1; bse<e1; bse+=64) {
            int m = e1-bse; if (m>64) m=64;
            int jv = (lane<m) ? col_b[bse+lane] : 0;
            int q=0;
            for (; 4*q+16 <= m; q+=4) {
              int j0=__shfl(jv,4*q+qt),    j1=__shfl(jv,4*q+4+qt);
              int j2=__shfl(jv,4*q+8+qt),  j3=__shfl(jv,4*q+12+qt);
              uint2 v0 = *(const uint2*)(hbb + ((((uint_t)j0)<<7) | goff));
              uint2 v1 = *(const uint2*)(hbb + ((((uint_t)j1)<<7) | goff));
              uint2 v2 = *(const uint2*)(hbb + ((((uint_t)j2)<<7) | goff));
              uint2 v3 = *(const uint2*)(hbb + ((((uint_t)j3)<<7) | goff));
              c01 += unpk(v0.x); c23 += unpk(v0.y);
              c01 += unpk(v1.x); c23 += unpk(v1.y);
              c01 += unpk(v2.x); c23 += unpk(v2.y);
              c01 += unpk(v3.x); c23 += unpk(v3.y);
            }
            for (; 4*q+qt < m; ++q) {
              int j=__shfl(jv,4*q+qt);
              uint2 v = *(const uint2*)(hbb + ((((uint_t)j)<<7) | goff));
              c01 += unpk(v.x); c23 += unpk(v.y);
            }
          }
        }
      }
      float df = fmaxf((float)degf, 1.f);
      float db = fmaxf((float)degb, 1.f);
      float s0v = 0.5f*(a01.x/df + c01.x/db);
      float s1v = 0.5f*(a01.y/df + c01.y/db);
      float s2v = 0.5f*(a23.x/df + c23.x/db);
      float s3v = 0.5f*(a23.y/df + c23.y/db);
      s0v += __shfl_xor(s0v,16); s0v += __shfl_xor(s0v,32);
      s1v += __shfl_xor(s1v,16); s1v += __shfl_xor(s1v,32);
      s2v += __shfl_xor(s2v,16); s2v += __shfl_xor(s2v,32);
      s3v += __shfl_xor(s3v,16); s3v += __shfl_xor(s3v,32);
      if (qt==0) {
        uint2 pk;
        pk.x = (uint_t)f2bf(s0v) | ((uint_t)f2bf(s1v) << 16);
        pk.y = (uint_t)f2bf(s2v) | ((uint_t)f2bf(s3v) << 16);
        *(uint2*)&srow[wid*4+nn][4*g] = pk;
      }
    }
  }
  __syncthreads();

  // ---------------- phase 2: MFMA gemm, wave = col-tile ----------------
  int lrow = lane & 15;        // A-row (local node) / C-feat within tile
  int lk   = lane >> 4;        // k-subgroup

  const ushort_t* sr = &srow[lrow][0];
  bf16x8 a0 = *(const bf16x8*)&sr[lk*8];        // s k 0..31
  bf16x8 a1 = *(const bf16x8*)&sr[32+lk*8];     // s k 32..63
  int arow = base + lrow; if (arow >= N) arow = N-1;
  const bf16x8* hfrag = (const bf16x8*)(hb + (size_t)arow*DD);
  bf16x8 a2 = hfrag[lk];                        // h k 64..95
  bf16x8 a3 = hfrag[4+lk];                      // h k 96..127

  const bf16x8* wbp = (const bf16x8*)Wb;
  int col = wid*16 + lrow;
  f32x4 acc = (f32x4){0.f,0.f,0.f,0.f};
  acc = __builtin_amdgcn_mfma_f32_16x16x32_bf16(a0, wbp[(0*4+lk)*64 + col], acc, 0,0,0);
  acc = __builtin_amdgcn_mfma_f32_16x16x32_bf16(a1, wbp[(1*4+lk)*64 + col], acc, 0,0,0);
  acc = __builtin_amdgcn_mfma_f32_16x16x32_bf16(a2, wbp[(2*4+lk)*64 + col], acc, 0,0,0);
  acc = __builtin_amdgcn_mfma_f32_16x16x32_bf16(a3, wbp[(3*4+lk)*64 + col], acc, 0,0,0);

  // epilogue: node = base + lk*4 + r, feat = wid*16 + lrow  [verified C/D mapping]
  int g0 = batch[(base < N) ? base : (N-1)];
  int bt[4];
  #pragma unroll
  for (int r=0; r<4; ++r) {
    int node = base + lk*4 + r;
    bt[r] = (node < N) ? batch[node] : -1;
  }
  {
    int feat = wid*16 + lrow;
    float bv = bias[feat];
    int gcur = -1; float ga=0.f, qa=0.f;
    #pragma unroll
    for (int r=0; r<4; ++r) {
      if (bt[r] < 0) break;
      float v = acc[r] + bv;
      tbs[lk*4+r][feat] = f2bf(v);
      if (bt[r] != gcur) {
        if (gcur >= 0) {
          int slot = gcur - g0;
          if (slot < 4) { atomicAdd(&lsum[slot][feat], ga); atomicAdd(&lsq[slot][feat], qa); }
          else { atomicAdd(&gsum[gcur*DD+feat], ga); atomicAdd(&gsq[gcur*DD+feat], qa); }
        }
        gcur = bt[r]; ga = 0.f; qa = 0.f;
      }
      ga += v; qa += v*v;
    }
    if (gcur >= 0) {
      int slot = gcur - g0;
      if (slot < 4) { atomicAdd(&lsum[slot][feat], ga); atomicAdd(&lsq[slot][feat], qa); }
      else { atomicAdd(&gsum[gcur*DD+feat], ga); atomicAdd(&gsq[gcur*DD+feat], qa); }
    }
  }
  __syncthreads();

  // flush per-block stats (typically 1-2 slots)
  int lastnode = base+15; if (lastnode >= N) lastnode = N-1;
  int nslots = batch[lastnode] - g0 + 1; if (nslots > 4) nslots = 4;
  for (int idx=threadIdx.x; idx < nslots*DD; idx += 256) {
    int s = idx >> 6, f = idx & 63;
    float vs = lsum[s][f], vq = lsq[s][f];
    if (vs != 0.f || vq != 0.f) {
      atomicAdd(&gsum[(g0+s)*DD+f], vs);
      atomicAdd(&gsq[(g0+s)*DD+f], vq);
    }
  }
  // vectorized tb store (16B per chunk): 16 rows x 8 chunks
  for (int c=threadIdx.x; c<128; c+=256) {
    int row = c >> 3, off = (c & 7)*8;
    int node = base + row;
    if (node < N) *(bf16x8*)&tb[(size_t)node*DD + off] = *(const bf16x8*)&tbs[row][off];
  }
}

// ---- vectorized GraphNorm (non-last layers): lane = (node-of-8, feat-octet), 16B chunks ----
__global__ __launch_bounds__(256) void norm2v_kernel(
    const ushort_t* __restrict__ tb,
    const float* __restrict__ gsum, const float* __restrict__ gsq,
    const int* __restrict__ cnt, const int* __restrict__ batch,
    const float* __restrict__ gw, const float* __restrict__ gb,
    const float* __restrict__ gms,
    ushort_t* __restrict__ hb, int resid, int N)
{
  int wv_id = (blockIdx.x*blockDim.x + threadIdx.x) >> 6;
  int lane = threadIdx.x & 63;
  int oct = lane & 7;          // feature octet (feats oct*8 .. +7)
  int no  = lane >> 3;         // node within 8-group
  int base = wv_id * NV_WN;
  if (base >= N) return;
  float wvv[8], bvv[8], msv[8];
  #pragma unroll
  for (int j=0;j<8;++j){ int f=oct*8+j; wvv[j]=gw[f]; bvv[j]=gb[f]; msv[j]=gms[f]; }
  int gcur=-1; float mean[8], rs[8];
  int end = base + NV_WN; if (end > N) end = N;
  for (int nb=base+no; nb<end; nb+=8) {
    int g = batch[nb];
    if (g != gcur) {
      float invc = 1.f/fmaxf((float)cnt[g],1.f);
      #pragma unroll
      for (int j=0;j<8;++j){
        int f = oct*8+j;
        float mn = gsum[g*DD+f]*invc;
        float mq = gsq[g*DD+f]*invc;
        float var = mq - msv[j]*(2.f-msv[j])*mn*mn;
        mean[j]=mn; rs[j]=rsqrtf(var+EPSV);
      }
      gcur=g;
    }
    bf16x8 tv = *(const bf16x8*)&tb[(size_t)nb*DD + oct*8];
    bf16x8 hv8 = *(const bf16x8*)&hb[(size_t)nb*DD + oct*8];
    bf16x8 outv;
    #pragma unroll
    for (int j=0;j<8;++j){
      float u = bf2f((ushort_t)tv[j]) - msv[j]*mean[j];
      float y = wvv[j]*u*rs[j] + bvv[j];
      y = (y>=0.f) ? y : SLOPE*y;
      float hvv = resid ? (bf2f((ushort_t)hv8[j]) + y) : y;
      outv[j] = (short)f2bf(hvv);
    }
    *(bf16x8*)&hb[(size_t)nb*DD + oct*8] = outv;
  }
}

// ---- last-layer GraphNorm (scalar, pool fused; runs once) ----
__global__ void norm2_last_kernel(const ushort_t* __restrict__ tb,
                             const float* __restrict__ gsum, const float* __restrict__ gsq,
                             const int* __restrict__ cnt, const int* __restrict__ batch,
                             const float* __restrict__ gw, const float* __restrict__ gb,
                             const float* __restrict__ gms,
                             const ushort_t* __restrict__ hb,
                             float* __restrict__ pout, int N)
{
  int wid = (blockIdx.x*blockDim.x + threadIdx.x) >> 6;
  int lane = threadIdx.x & 63;
  int base = wid*NRM_NPW;
  if (base >= N) return;
  float wv = gw[lane], bv = gb[lane], msv = gms[lane];
  float cms = msv*(2.f - msv);
  int gcur=-1; float rs=0.f, mean=0.f, pacc=0.f;
  int end = base+NRM_NPW; if (end>N) end=N;
  for (int node=base; node<end; ++node) {
    int g = batch[node];
    if (g!=gcur) {
      if (gcur>=0) atomicAdd(&pout[gcur*DD+lane], pacc);
      pacc = 0.f;
      float invc = 1.f/fmaxf((float)cnt[g],1.f);
      mean = gsum[g*DD+lane]*invc;
      float msq = gsq[g*DD+lane]*invc;
      float var = msq - cms*mean*mean;
      rs = rsqrtf(var + EPSV);
      gcur=g;
    }
    float u = bf2f(tb[(size_t)node*DD+lane]) - msv*mean;
    float y = wv*u*rs + bv;
    y = (y>=0.f) ? y : SLOPE*y;
    pacc += bf2f(hb[(size_t)node*DD+lane]) + y;   // resid always true on last layer (L>2)
  }
  if (gcur>=0) atomicAdd(&pout[gcur*DD+lane], pacc);
}

__global__ void finalize_kernel(const float* __restrict__ pout, const int* __restrict__ cnt,
                                float* __restrict__ out)
{
  int i = blockIdx.x*blockDim.x + threadIdx.x;
  if (i < GG*DD) {
    float invc = 1.f/fmaxf((float)cnt[i>>6],1.f);
    out[i] = pout[i]*invc;
  }
}

extern "C" void kernel_launch(void* const* d_in, const int* in_sizes, int n_in,
                              void* d_out, int out_size, void* d_ws, size_t ws_size,
                              hipStream_t stream)
{
  const float* x    = (const float*)d_in[0];
  const int*  ei    = (const int*)d_in[1];
  const int*  batch = (const int*)d_in[2];
  const float* W_l  = (const float*)d_in[3];
  const float* W_r  = (const float*)d_in[4];
  const float* bias = (const float*)d_in[5];
  const float* gn_w = (const float*)d_in[6];
  const float* gn_b = (const float*)d_in[7];
  const float* gn_ms= (const float*)d_in[8];

  int N = in_sizes[2];
  int E = in_sizes[1]/2;
  int L = in_sizes[5]/DD;
  const int* src = ei;
  const int* dst = ei + E;

  // ---- workspace layout: zero-zone first (single memset) ----
  char* p = (char*)d_ws;
  int*   cnt   = (int*)p;   p += GG*4;
  float* gsum  = (float*)p; p += (size_t)L*GG*DD*4;
  float* gsq   = (float*)p; p += (size_t)L*GG*DD*4;
  float* pout  = (float*)p; p += GG*DD*4;
  size_t zeroBytes = (char*)p - (char*)d_ws;

  int* staged  = (int*)p; p += (size_t)2*E*4;             // packed CSR records (12.8MB)
  ushort_t* tb    = (ushort_t*)p; p += (size_t)N*DD*2;
  ushort_t* hb    = (ushort_t*)p; p += (size_t)N*DD*2;
  ushort_t* wb    = (ushort_t*)p; p += (size_t)L*8192*2;  // packed MFMA weights
  int* rp_f    = (int*)p; p += (size_t)(N+1)*4;
  int* rp_b    = (int*)p; p += (size_t)(N+1)*4;
  int* col_f   = (int*)p; p += (size_t)E*4;
  int* col_b   = (int*)p; p += (size_t)E*4;
  int* hist    = (int*)p; p += (size_t)2*NRANGE*ABLK*4;   // 2MB
  int* offs    = (int*)p; p += (size_t)2*NRANGE*ABLK*4;   // 2MB
  int* partial = (int*)p; p += 512*4;

  hipMemsetAsync(d_ws, 0, zeroBytes, stream);

  const int M = 2*NRANGE*ABLK;  // 524288
  bin_count_kernel<<<ABLK, 256, 0, stream>>>(src, dst, hist, E);
  block_sum_kernel<<<(M+1023)/1024, 1024, 0, stream>>>(hist, partial, M);
  scan_partial_kernel<<<1, 512, 0, stream>>>(partial, (M+1023)/1024);
  scan_apply_kernel<<<(M+1023)/1024, 1024, 0, stream>>>(hist, partial, offs, M);
  bin_scatter_kernel<<<ABLK, 256, 0, stream>>>(src, dst, offs, staged, E);
  range_fill_kernel<<<2*NRANGE, 256, 0, stream>>>(staged, offs, rp_f, rp_b, col_f, col_b, N, E);

  cnt_kernel<<<391, 256, 0, stream>>>(batch, cnt, N);
  tobf16_kernel<<<2048, 256, 0, stream>>>(x, hb, N*DD);
  wpack_kernel<<<L, 256, 0, stream>>>(W_l, W_r, wb);

  int ggBlocks = (N + 15)/16;          // 16 nodes per fused block
  int nvWaves = (N + NV_WN-1)/NV_WN;
  int nvBlocks = (nvWaves+3)/4;
  int nrmWaves = (N + NRM_NPW-1)/NRM_NPW;
  int nrmBlocks = (nrmWaves+3)/4;

  for (int i=0; i<L; ++i) {
    float* gsum_i = gsum + (size_t)i*GG*DD;
    float* gsq_i  = gsq  + (size_t)i*GG*DD;
    gg_kernel<<<ggBlocks, 256, 0, stream>>>(hb, rp_f, col_f, rp_b, col_b,
                                            wb + (size_t)i*8192, bias+(size_t)i*DD,
                                            batch, tb, gsum_i, gsq_i, N);
    if (i < L-1) {
      norm2v_kernel<<<nvBlocks, 256, 0, stream>>>(tb, gsum_i, gsq_i, cnt, batch,
                                                  gn_w+(size_t)i*DD, gn_b+(size_t)i*DD,
                                                  gn_ms+(size_t)i*DD, hb, (i>=2)?1:0, N);
    } else {
      norm2_last_kernel<<<nrmBlocks, 256, 0, stream>>>(tb, gsum_i, gsq_i, cnt, batch,
                                                       gn_w+(size_t)i*DD, gn_b+(size_t)i*DD,
                                                       gn_ms+(size_t)i*DD, hb, pout, N);
    }
  }
  finalize_kernel<<<16, 256, 0, stream>>>(pout, cnt, (float*)d_out);
}